// Round 2
// baseline (8204.898 us; speedup 1.0000x reference)
//
#include <hip/hip_runtime.h>
#include <hip/hip_bf16.h>
#include <math.h>

#define B 16
#define L 96
#define N 512
#define D 512
#define H 8
#define E 64
#define DFF 2048
#define T 516
#define PRED 96
#define NMARK 4

// ---- workspace layout (floats). Total 21,118,976 floats = 84.5 MB ----
// Liveness-packed: xt aliases Q, nt/tok alias K, ctx/dec alias Q,
// ffn chunk spans Q+K (all dead at that point).
#define OFF_MEAN 0            // B*N = 8192
#define OFF_STD  8192         // B*N = 8192
#define OFF_GD   16384        // B*N*N = 4,194,304
#define OFF_X    4210688      // B*T*D = 4,227,072
#define OFF_Q    8437760      // B*T*D
#define OFF_K    12664832     // B*T*D
#define OFF_V    16891904     // B*T*D  -> end 21,118,976 floats (84,475,904 B)

__device__ __forceinline__ float block_reduce_sum256(float v, float* red) {
    int tid = threadIdx.x;
    red[tid] = v; __syncthreads();
    for (int off = 128; off > 0; off >>= 1) {
        if (tid < off) red[tid] += red[tid + off];
        __syncthreads();
    }
    float r = red[0];
    __syncthreads();
    return r;
}

__device__ __forceinline__ float block_reduce_max256(float v, float* red) {
    int tid = threadIdx.x;
    red[tid] = v; __syncthreads();
    for (int off = 128; off > 0; off >>= 1) {
        if (tid < off) red[tid] = fmaxf(red[tid], red[tid + off]);
        __syncthreads();
    }
    float r = red[0];
    __syncthreads();
    return r;
}

// ---------- RevIN stats ----------
__global__ void revin_stats_kernel(const float* __restrict__ x, float* __restrict__ mean,
                                   float* __restrict__ stdv) {
    int i = blockIdx.x * blockDim.x + threadIdx.x;
    if (i >= B * N) return;
    int b = i >> 9;
    int n = i & (N - 1);
    const float* p = x + (size_t)b * L * N + n;
    float s = 0.f, ss = 0.f;
    for (int l = 0; l < L; ++l) {
        float v = p[(size_t)l * N];
        s += v; ss += v * v;
    }
    float m = s / (float)L;
    float var = ss / (float)L - m * m;
    mean[i] = m;
    stdv[i] = sqrtf(fmaxf(var, 0.f) + 1e-5f);
}

// ---------- normalize + transpose: xt[b,n,l] ----------
__global__ void norm_transpose_kernel(const float* __restrict__ x, const float* __restrict__ mean,
                                      const float* __restrict__ stdv, const float* __restrict__ gamma,
                                      const float* __restrict__ beta, float* __restrict__ xt) {
    int idx = blockIdx.x * blockDim.x + threadIdx.x;
    if (idx >= B * N * L) return;
    int l = idx % L;
    int n = (idx / L) % N;
    int b = idx / (L * N);
    float v = x[((size_t)b * L + l) * N + n];
    int bn = b * N + n;
    xt[idx] = (v - mean[bn]) / stdv[bn] * gamma[n] + beta[n];
}

// ---------- trend + normalized trend rows nt[b,n,l] ----------
__global__ void trend_nt_kernel(const float* __restrict__ xt, const float* __restrict__ tp_w1,
                                const float* __restrict__ tp_b1, const float* __restrict__ tp_w2,
                                const float* __restrict__ tp_b2, float* __restrict__ nt) {
    int bn = blockIdx.x;
    __shared__ float xr[96];
    __shared__ float P[97];
    __shared__ float wt[4];
    __shared__ float tr[96];
    __shared__ float nrm;
    int tid = threadIdx.x;
    if (tid < 96) xr[tid] = xt[(size_t)bn * 96 + tid];
    __syncthreads();
    if (tid == 0) {
        float s = 0.f, ss = 0.f;
        P[0] = 0.f;
        for (int l = 0; l < 96; ++l) { s += xr[l]; P[l + 1] = s; ss += xr[l] * xr[l]; }
        float m = s / 96.f;
        float var = ss / 96.f - m * m;
        float sd = sqrtf(fmaxf(var, 0.f) + 1e-6f);
        float h[16];
        for (int j = 0; j < 16; ++j) {
            float t = m * tp_w1[j] + sd * tp_w1[16 + j] + tp_b1[j];
            h[j] = fmaxf(t, 0.f);
        }
        float lg[4];
        for (int w = 0; w < 4; ++w) {
            float t = tp_b2[w];
            for (int j = 0; j < 16; ++j) t += h[j] * tp_w2[j * 4 + w];
            lg[w] = t;
        }
        float mx = fmaxf(fmaxf(lg[0], lg[1]), fmaxf(lg[2], lg[3]));
        float es = 0.f;
        for (int w = 0; w < 4; ++w) { lg[w] = expf(lg[w] - mx); es += lg[w]; }
        for (int w = 0; w < 4; ++w) wt[w] = lg[w] / es;
    }
    __syncthreads();
    const int WS[4] = {4, 8, 12, 24};
    if (tid < 96) {
        int l = tid;
        float t = 0.f;
        for (int wi = 0; wi < 4; ++wi) {
            int w = WS[wi];
            int lo = l - w + 1;
            float s;
            if (lo >= 0) s = P[l + 1] - P[lo];
            else         s = P[l + 1] - P[0] + (float)(-lo) * xr[0];
            t += (s / (float)w) * wt[wi];
        }
        tr[l] = t;
    }
    __syncthreads();
    if (tid == 0) {
        float s = 0.f;
        for (int l = 0; l < 96; ++l) s += tr[l] * tr[l];
        nrm = fmaxf(sqrtf(s), 1e-12f);
    }
    __syncthreads();
    if (tid < 96) nt[(size_t)bn * 96 + tid] = tr[tid] / nrm;
}

// ---------- guidance: sigmoid(nt @ nt^T) ----------
__global__ void guide_kernel(const float* __restrict__ nt, float* __restrict__ guide) {
    __shared__ float ri[16][97];
    __shared__ float rj[16][97];
    int b = blockIdx.z;
    int i0 = blockIdx.y * 16;
    int j0 = blockIdx.x * 16;
    int tx = threadIdx.x, ty = threadIdx.y;
    int tid = ty * 16 + tx;
    for (int t = tid; t < 16 * 96; t += 256) {
        int r = t / 96, c = t % 96;
        ri[r][c] = nt[((size_t)b * N + i0 + r) * 96 + c];
        rj[r][c] = nt[((size_t)b * N + j0 + r) * 96 + c];
    }
    __syncthreads();
    float acc = 0.f;
    for (int k = 0; k < 96; ++k) acc += ri[ty][k] * rj[tx][k];
    guide[((size_t)b * N + i0 + ty) * N + j0 + tx] = 1.f / (1.f + expf(-acc));
}

// ---------- build tokens [B,T,L] ----------
__global__ void build_tok_kernel(const float* __restrict__ xt, const float* __restrict__ xmark,
                                 float* __restrict__ tok) {
    int idx = blockIdx.x * blockDim.x + threadIdx.x;
    if (idx >= B * T * L) return;
    int l = idx % L;
    int t = (idx / L) % T;
    int b = idx / (L * T);
    float v;
    if (t < N) v = xt[((size_t)b * N + t) * L + l];
    else       v = xmark[((size_t)b * L + l) * NMARK + (t - N)];
    tok[idx] = v;
}

// ---------- generic fp32 GEMM: C = [res +] act(A@W + bias) ----------
// res/C may be the same buffer (element-wise read-then-write per thread).
#define BM 64
#define BN 64
#define BK 16
__global__ void gemm_kernel(const float* __restrict__ A, const float* __restrict__ W,
                            const float* __restrict__ bias, const float* __restrict__ res,
                            float* __restrict__ C, int M, int Nn, int K, int act) {
    __shared__ float As[BK][BM + 1];
    __shared__ float Ws[BK][BN + 1];
    int bm = blockIdx.y * BM;
    int bn = blockIdx.x * BN;
    int tx = threadIdx.x & 15;
    int ty = threadIdx.x >> 4;
    float acc[4][4] = {};
    for (int k0 = 0; k0 < K; k0 += BK) {
        for (int i = threadIdx.x; i < BM * BK; i += 256) {
            int m = i >> 4, kk = i & 15;
            int gm = bm + m, gk = k0 + kk;
            As[kk][m] = (gm < M && gk < K) ? A[(size_t)gm * K + gk] : 0.f;
        }
        for (int i = threadIdx.x; i < BK * BN; i += 256) {
            int kk = i >> 6, n = i & 63;
            int gk = k0 + kk, gn = bn + n;
            Ws[kk][n] = (gk < K && gn < Nn) ? W[(size_t)gk * Nn + gn] : 0.f;
        }
        __syncthreads();
        #pragma unroll
        for (int kk = 0; kk < BK; ++kk) {
            float a[4], w[4];
            #pragma unroll
            for (int i = 0; i < 4; ++i) a[i] = As[kk][ty * 4 + i];
            #pragma unroll
            for (int j = 0; j < 4; ++j) w[j] = Ws[kk][tx * 4 + j];
            #pragma unroll
            for (int i = 0; i < 4; ++i)
                #pragma unroll
                for (int j = 0; j < 4; ++j) acc[i][j] += a[i] * w[j];
        }
        __syncthreads();
    }
    for (int i = 0; i < 4; ++i) {
        int gm = bm + ty * 4 + i;
        if (gm >= M) continue;
        for (int j = 0; j < 4; ++j) {
            int gn = bn + tx * 4 + j;
            if (gn >= Nn) continue;
            float v = acc[i][j] + (bias ? bias[gn] : 0.f);
            if (act == 1) v = 0.5f * v * (1.f + erff(v * 0.70710678118654752f));
            if (res) v += res[(size_t)gm * Nn + gn];
            C[(size_t)gm * Nn + gn] = v;
        }
    }
}

// ---------- attention: one block per (b,h,l) row. ctx may alias q ----------
__global__ void attn_kernel(const float* __restrict__ q, const float* __restrict__ k,
                            const float* __restrict__ v, const float* __restrict__ guide,
                            float* __restrict__ ctx) {
    int bid = blockIdx.x;
    int l = bid % T;
    int h = (bid / T) % H;
    int b = bid / (T * H);
    int tid = threadIdx.x;
    __shared__ float qs[64];
    __shared__ float sc[T];
    __shared__ float red[256];
    __shared__ float part[4 * 64];
    const float* kbase = k + (size_t)b * T * D + h * 64;
    const float* vbase = v + (size_t)b * T * D + h * 64;
    if (tid < 64) qs[tid] = q[((size_t)b * T + l) * D + h * 64 + tid];
    __syncthreads();
    float lmax = -1e30f;
    for (int s = tid; s < T; s += 256) {
        const float* kr = kbase + (size_t)s * D;
        float d = 0.f;
        #pragma unroll
        for (int e = 0; e < 64; ++e) d += qs[e] * kr[e];
        d *= 0.125f;
        sc[s] = d;
        lmax = fmaxf(lmax, d);
    }
    float mx = block_reduce_max256(lmax, red);
    float lsum = 0.f;
    for (int s = tid; s < T; s += 256) {
        float p = expf(sc[s] - mx);
        sc[s] = p;
        lsum += p;
    }
    __syncthreads();
    float sp = block_reduce_sum256(lsum, red);
    float inv_sp = 1.f / sp;
    const float* grow = guide + ((size_t)b * N + l) * N;
    float lsum2 = 0.f;
    __syncthreads();
    for (int s = tid; s < T; s += 256) {
        float g = (l < N && s < N) ? grow[s] : 0.5f;
        float t = sc[s] * inv_sp * g;
        sc[s] = t;
        lsum2 += t;
    }
    __syncthreads();
    float st = block_reduce_sum256(lsum2, red);
    float inv = 1.f / (st + 1e-6f);
    int e = tid & 63;
    int grp = tid >> 6;
    float acc = 0.f;
    for (int s = grp; s < T; s += 4) acc += sc[s] * vbase[(size_t)s * D + e];
    part[grp * 64 + e] = acc;
    __syncthreads();
    if (tid < 64) {
        float r = (part[tid] + part[64 + tid] + part[128 + tid] + part[192 + tid]) * inv;
        ctx[((size_t)b * T + l) * D + h * 64 + tid] = r;
    }
}

// ---------- layernorm over D per row (in-place safe) ----------
__global__ void ln_kernel(const float* __restrict__ in, const float* __restrict__ g,
                          const float* __restrict__ bb, float* __restrict__ out) {
    int row = blockIdx.x;
    int tid = threadIdx.x;
    __shared__ float red[256];
    float v0 = in[(size_t)row * D + tid];
    float v1 = in[(size_t)row * D + 256 + tid];
    float s = block_reduce_sum256(v0 + v1, red);
    float ss = block_reduce_sum256(v0 * v0 + v1 * v1, red);
    float m = s / (float)D;
    float var = ss / (float)D - m * m;
    float rstd = rsqrtf(fmaxf(var, 0.f) + 1e-5f);
    out[(size_t)row * D + tid]       = (v0 - m) * rstd * g[tid] + bb[tid];
    out[(size_t)row * D + 256 + tid] = (v1 - m) * rstd * g[256 + tid] + bb[256 + tid];
}

// ---------- final: transpose + RevIN inverse ----------
__global__ void revin_inv_kernel(const float* __restrict__ dec, const float* __restrict__ beta,
                                 const float* __restrict__ gamma, const float* __restrict__ mean,
                                 const float* __restrict__ stdv, float* __restrict__ out) {
    int idx = blockIdx.x * blockDim.x + threadIdx.x;
    if (idx >= B * PRED * N) return;
    int n = idx % N;
    int p = (idx / N) % PRED;
    int b = idx / (N * PRED);
    float v = dec[((size_t)b * T + n) * PRED + p];
    int bn = b * N + n;
    out[idx] = (v - beta[n]) / (gamma[n] + 1e-5f) * stdv[bn] + mean[bn];
}

extern "C" void kernel_launch(void* const* d_in, const int* in_sizes, int n_in,
                              void* d_out, int out_size, void* d_ws, size_t ws_size,
                              hipStream_t stream) {
    const float* x_enc  = (const float*)d_in[0];
    const float* x_mark = (const float*)d_in[1];
    const float* gamma  = (const float*)d_in[4];
    const float* beta   = (const float*)d_in[5];
    const float* tp_w1  = (const float*)d_in[6];
    const float* tp_b1  = (const float*)d_in[7];
    const float* tp_w2  = (const float*)d_in[8];
    const float* tp_b2  = (const float*)d_in[9];
    const float* emb_w  = (const float*)d_in[10];
    const float* emb_b  = (const float*)d_in[11];
    const float* wq = (const float*)d_in[12];
    const float* bq = (const float*)d_in[13];
    const float* wk = (const float*)d_in[14];
    const float* bk = (const float*)d_in[15];
    const float* wv = (const float*)d_in[16];
    const float* bv = (const float*)d_in[17];
    const float* wo = (const float*)d_in[18];
    const float* bo = (const float*)d_in[19];
    const float* w1 = (const float*)d_in[20];
    const float* b1 = (const float*)d_in[21];
    const float* w2 = (const float*)d_in[22];
    const float* b2 = (const float*)d_in[23];
    const float* ln1g = (const float*)d_in[24];
    const float* ln1b = (const float*)d_in[25];
    const float* ln2g = (const float*)d_in[26];
    const float* ln2b = (const float*)d_in[27];
    const float* normg = (const float*)d_in[28];
    const float* normb = (const float*)d_in[29];
    const float* proj_w = (const float*)d_in[30];
    const float* proj_b = (const float*)d_in[31];

    float* ws   = (float*)d_ws;
    float* mean = ws + OFF_MEAN;
    float* stdv = ws + OFF_STD;
    float* gd   = ws + OFF_GD;
    float* x    = ws + OFF_X;
    float* q    = ws + OFF_Q;
    float* k    = ws + OFF_K;
    float* v    = ws + OFF_V;
    float* xt   = q;      // dead before q first written
    float* nt   = k;      // dead before k first written
    float* tok  = k;      // dead before k first written (after nt's last use)
    float* ctx  = q;      // attn block reads its own q slot before writing it
    float* ffn  = q;      // chunk buffer spans q+k regions (both dead in FFN)
    float* dec  = q;      // dead at projection time

    revin_stats_kernel<<<(B * N + 255) / 256, 256, 0, stream>>>(x_enc, mean, stdv);
    norm_transpose_kernel<<<(B * N * L + 255) / 256, 256, 0, stream>>>(x_enc, mean, stdv, gamma, beta, xt);
    trend_nt_kernel<<<B * N, 128, 0, stream>>>(xt, tp_w1, tp_b1, tp_w2, tp_b2, nt);
    guide_kernel<<<dim3(N / 16, N / 16, B), dim3(16, 16), 0, stream>>>(nt, gd);
    build_tok_kernel<<<(B * T * L + 255) / 256, 256, 0, stream>>>(xt, x_mark, tok);

    const int M = B * T;       // 8256
    const int MC = M / 2;      // 4128 (FFN row-chunk)
    gemm_kernel<<<dim3(D / 64, (M + 63) / 64), 256, 0, stream>>>(tok, emb_w, emb_b, nullptr, x, M, D, L, 0);

    for (int i = 0; i < 2; ++i) {
        const float* wqi = wq + (size_t)i * D * D;
        const float* wki = wk + (size_t)i * D * D;
        const float* wvi = wv + (size_t)i * D * D;
        const float* woi = wo + (size_t)i * D * D;
        gemm_kernel<<<dim3(D / 64, (M + 63) / 64), 256, 0, stream>>>(x, wqi, bq + i * D, nullptr, q, M, D, D, 0);
        gemm_kernel<<<dim3(D / 64, (M + 63) / 64), 256, 0, stream>>>(x, wki, bk + i * D, nullptr, k, M, D, D, 0);
        gemm_kernel<<<dim3(D / 64, (M + 63) / 64), 256, 0, stream>>>(x, wvi, bv + i * D, nullptr, v, M, D, D, 0);
        attn_kernel<<<B * H * T, 256, 0, stream>>>(q, k, v, gd, ctx);
        // x += ctx @ wo + bo   (in-place residual)
        gemm_kernel<<<dim3(D / 64, (M + 63) / 64), 256, 0, stream>>>(ctx, woi, bo + i * D, x, x, M, D, D, 0);
        ln_kernel<<<M, 256, 0, stream>>>(x, ln1g + i * D, ln1b + i * D, x);
        // FFN in 2 row-chunks; hidden acts reuse dead q+k regions
        for (int c = 0; c < 2; ++c) {
            float* xc = x + (size_t)c * MC * D;
            gemm_kernel<<<dim3(DFF / 64, (MC + 63) / 64), 256, 0, stream>>>(xc, w1 + (size_t)i * D * DFF, b1 + i * DFF, nullptr, ffn, MC, DFF, D, 1);
            gemm_kernel<<<dim3(D / 64, (MC + 63) / 64), 256, 0, stream>>>(ffn, w2 + (size_t)i * DFF * D, b2 + i * D, xc, xc, MC, D, DFF, 0);
        }
        ln_kernel<<<M, 256, 0, stream>>>(x, ln2g + i * D, ln2b + i * D, x);
    }

    ln_kernel<<<M, 256, 0, stream>>>(x, normg, normb, x);
    gemm_kernel<<<dim3((PRED + 63) / 64, (M + 63) / 64), 256, 0, stream>>>(x, proj_w, proj_b, nullptr, dec, M, PRED, D, 0);
    revin_inv_kernel<<<(B * PRED * N + 255) / 256, 256, 0, stream>>>(dec, beta, gamma, mean, stdv, (float*)d_out);
}

// Round 4
// 1381.412 us; speedup vs baseline: 5.9395x; 5.9395x over previous
//
#include <hip/hip_runtime.h>
#include <hip/hip_bf16.h>
#include <math.h>

#define B 16
#define L 96
#define N 512
#define D 512
#define H 8
#define E 64
#define DFF 2048
#define T 516
#define PRED 96
#define NMARK 4
#define TPAD 544   // P-strip LDS stride (>= 17*32 = 544)
#define VTS 528    // vt row stride (tokens, padded from 516)

typedef __attribute__((ext_vector_type(8))) short bf16x8;
typedef __attribute__((ext_vector_type(4))) float f32x4;

// ---- workspace layout (BYTE offsets). Total 80,412,672 B = 76.7 MB ----
// (round 2 proved >= 84,475,904 B available)
#define WS_MEAN 0              // f32 [B,N]
#define WS_STD  32768          // f32 [B,N]
#define WS_GD   65536          // bf16 [B,N,N] = 8,388,608 B
#define WS_X    8454144        // f32 [B,T,D] = 16,908,288 B (residual master)
#define WS_XB   25362432       // bf16 [B,T,D] (bf16 shadow; also ctxb)
#define WS_WTS  33816576       // bf16 transposed weights, 12,779,520 B
#define WS_QB   46596096       // bf16 [B,T,D]; also tokb(bf16), dec(f32), ffn base
#define WS_KB   55050240       // bf16 [B,T,D]; also xt(f32)
#define WS_VT   63504384       // bf16 [B,H,64,VTS] = 8,650,752 B; also nt(f32)
#define VT_BYTES 8650752
// ffnb = WS_QB .. WS_QB + 8256*2048*2 = 80,412,672 (spans qb,kb,vt,+extra)

// weight-arena element offsets (bf16 elements from WS_WTS)
#define WT_WQ   0u          // [2][512][512] transposed per layer
#define WT_WK   524288u
#define WT_WV   1048576u
#define WT_WO   1572864u
#define WT_W1   2097152u    // [2][2048][512]
#define WT_W2   4194304u    // [2][512][2048]
#define WT_EMB  6291456u    // [512][96]
#define WT_PROJ 6340608u    // [96][512]

__device__ __forceinline__ float block_reduce_sum256(float v, float* red) {
    int tid = threadIdx.x;
    red[tid] = v; __syncthreads();
    for (int off = 128; off > 0; off >>= 1) {
        if (tid < off) red[tid] += red[tid + off];
        __syncthreads();
    }
    float r = red[0];
    __syncthreads();
    return r;
}

// ---------- RevIN stats ----------
__global__ void revin_stats_kernel(const float* __restrict__ x, float* __restrict__ mean,
                                   float* __restrict__ stdv) {
    int i = blockIdx.x * blockDim.x + threadIdx.x;
    if (i >= B * N) return;
    int b = i >> 9;
    int n = i & (N - 1);
    const float* p = x + (size_t)b * L * N + n;
    float s = 0.f, ss = 0.f;
    for (int l = 0; l < L; ++l) {
        float v = p[(size_t)l * N];
        s += v; ss += v * v;
    }
    float m = s / (float)L;
    float var = ss / (float)L - m * m;
    mean[i] = m;
    stdv[i] = sqrtf(fmaxf(var, 0.f) + 1e-5f);
}

// ---------- normalize + transpose: xt[b,n,l] (f32) ----------
__global__ void norm_transpose_kernel(const float* __restrict__ x, const float* __restrict__ mean,
                                      const float* __restrict__ stdv, const float* __restrict__ gamma,
                                      const float* __restrict__ beta, float* __restrict__ xt) {
    int idx = blockIdx.x * blockDim.x + threadIdx.x;
    if (idx >= B * N * L) return;
    int l = idx % L;
    int n = (idx / L) % N;
    int b = idx / (L * N);
    float v = x[((size_t)b * L + l) * N + n];
    int bn = b * N + n;
    xt[idx] = (v - mean[bn]) / stdv[bn] * gamma[n] + beta[n];
}

// ---------- trend + normalized trend rows nt[b,n,l] (f32) ----------
__global__ void trend_nt_kernel(const float* __restrict__ xt, const float* __restrict__ tp_w1,
                                const float* __restrict__ tp_b1, const float* __restrict__ tp_w2,
                                const float* __restrict__ tp_b2, float* __restrict__ nt) {
    int bn = blockIdx.x;
    __shared__ float xr[96];
    __shared__ float P[97];
    __shared__ float wt[4];
    __shared__ float tr[96];
    __shared__ float nrm;
    int tid = threadIdx.x;
    if (tid < 96) xr[tid] = xt[(size_t)bn * 96 + tid];
    __syncthreads();
    if (tid == 0) {
        float s = 0.f, ss = 0.f;
        P[0] = 0.f;
        for (int l = 0; l < 96; ++l) { s += xr[l]; P[l + 1] = s; ss += xr[l] * xr[l]; }
        float m = s / 96.f;
        float var = ss / 96.f - m * m;
        float sd = sqrtf(fmaxf(var, 0.f) + 1e-6f);
        float h[16];
        for (int j = 0; j < 16; ++j) {
            float t = m * tp_w1[j] + sd * tp_w1[16 + j] + tp_b1[j];
            h[j] = fmaxf(t, 0.f);
        }
        float lg[4];
        for (int w = 0; w < 4; ++w) {
            float t = tp_b2[w];
            for (int j = 0; j < 16; ++j) t += h[j] * tp_w2[j * 4 + w];
            lg[w] = t;
        }
        float mx = fmaxf(fmaxf(lg[0], lg[1]), fmaxf(lg[2], lg[3]));
        float es = 0.f;
        for (int w = 0; w < 4; ++w) { lg[w] = expf(lg[w] - mx); es += lg[w]; }
        for (int w = 0; w < 4; ++w) wt[w] = lg[w] / es;
    }
    __syncthreads();
    const int WS[4] = {4, 8, 12, 24};
    if (tid < 96) {
        int l = tid;
        float t = 0.f;
        for (int wi = 0; wi < 4; ++wi) {
            int w = WS[wi];
            int lo = l - w + 1;
            float s;
            if (lo >= 0) s = P[l + 1] - P[lo];
            else         s = P[l + 1] - P[0] + (float)(-lo) * xr[0];
            t += (s / (float)w) * wt[wi];
        }
        tr[l] = t;
    }
    __syncthreads();
    if (tid == 0) {
        float s = 0.f;
        for (int l = 0; l < 96; ++l) s += tr[l] * tr[l];
        nrm = fmaxf(sqrtf(s), 1e-12f);
    }
    __syncthreads();
    if (tid < 96) nt[(size_t)bn * 96 + tid] = tr[tid] / nrm;
}

// ---------- guidance: sigmoid(nt @ nt^T) -> bf16 ----------
__global__ void guide_kernel(const float* __restrict__ nt, __hip_bfloat16* __restrict__ guide) {
    __shared__ float ri[16][97];
    __shared__ float rj[16][97];
    int b = blockIdx.z;
    int i0 = blockIdx.y * 16;
    int j0 = blockIdx.x * 16;
    int tx = threadIdx.x, ty = threadIdx.y;
    int tid = ty * 16 + tx;
    for (int t = tid; t < 16 * 96; t += 256) {
        int r = t / 96, c = t % 96;
        ri[r][c] = nt[((size_t)b * N + i0 + r) * 96 + c];
        rj[r][c] = nt[((size_t)b * N + j0 + r) * 96 + c];
    }
    __syncthreads();
    float acc = 0.f;
    for (int k = 0; k < 96; ++k) acc += ri[ty][k] * rj[tx][k];
    guide[((size_t)b * N + i0 + ty) * N + j0 + tx] =
        __float2bfloat16(1.f / (1.f + expf(-acc)));
}

// ---------- build tokens [B,T,L] bf16 ----------
__global__ void build_tok_kernel(const float* __restrict__ xt, const float* __restrict__ xmark,
                                 __hip_bfloat16* __restrict__ tok) {
    int idx = blockIdx.x * blockDim.x + threadIdx.x;
    if (idx >= B * T * L) return;
    int l = idx % L;
    int t = (idx / L) % T;
    int b = idx / (L * T);
    float v;
    if (t < N) v = xt[((size_t)b * N + t) * L + l];
    else       v = xmark[((size_t)b * L + l) * NMARK + (t - N)];
    tok[idx] = __float2bfloat16(v);
}

// ---------- weight transpose+convert: fp32 [K,N] -> bf16 [N,K] ----------
__global__ void wconv_kernel(const float* __restrict__ wq, const float* __restrict__ wk,
                             const float* __restrict__ wv, const float* __restrict__ wo,
                             const float* __restrict__ w1, const float* __restrict__ w2,
                             const float* __restrict__ emb, const float* __restrict__ proj,
                             __hip_bfloat16* __restrict__ wts) {
    int bid = blockIdx.x;
    const float* src; __hip_bfloat16* dst; int K, Nn, tloc;
    if (bid < 2048) {        // wq/wk/wv/wo: 512 tiles each (2 layers x 256)
        int seg = bid >> 9;
        int t = bid & 511;
        int layer = t >> 8;
        tloc = t & 255;
        K = 512; Nn = 512;
        const float* bases[4] = {wq, wk, wv, wo};
        src = bases[seg] + (size_t)layer * 512 * 512;
        dst = wts + (seg == 0 ? WT_WQ : seg == 1 ? WT_WK : seg == 2 ? WT_WV : WT_WO)
                  + (size_t)layer * 512 * 512;
    } else if (bid < 4096) { // w1
        int t = bid - 2048;
        int layer = t >> 10;
        tloc = t & 1023;
        K = 512; Nn = 2048;
        src = w1 + (size_t)layer * 512 * 2048;
        dst = wts + WT_W1 + (size_t)layer * 2048 * 512;
    } else if (bid < 6144) { // w2
        int t = bid - 4096;
        int layer = t >> 10;
        tloc = t & 1023;
        K = 2048; Nn = 512;
        src = w2 + (size_t)layer * 2048 * 512;
        dst = wts + WT_W2 + (size_t)layer * 512 * 2048;
    } else if (bid < 6192) { // emb [96,512]
        tloc = bid - 6144;
        K = 96; Nn = 512;
        src = emb; dst = wts + WT_EMB;
    } else {                 // proj [512,96]
        tloc = bid - 6192;
        K = 512; Nn = 96;
        src = proj; dst = wts + WT_PROJ;
    }
    int ntile = Nn >> 5;
    int tk = tloc / ntile, tn = tloc % ntile;
    int k0 = tk * 32, n0 = tn * 32;
    __shared__ float ld[32][33];
    int tid = threadIdx.x;
    for (int i = tid; i < 1024; i += 256) {
        int r = i >> 5, c = i & 31;
        ld[r][c] = src[(size_t)(k0 + r) * Nn + n0 + c];
    }
    __syncthreads();
    for (int i = tid; i < 1024; i += 256) {
        int r = i >> 5, c = i & 31;
        dst[(size_t)(n0 + r) * K + k0 + c] = __float2bfloat16(ld[c][r]);
    }
}

// ---------- MFMA bf16 GEMM: 128x128 tile, BK=32, 4 waves ----------
__global__ __launch_bounds__(256, 2) void mfma_gemm(
    const __hip_bfloat16* __restrict__ A, const __hip_bfloat16* __restrict__ Wt,
    const float* __restrict__ bias, const float* __restrict__ res,
    float* __restrict__ outF, __hip_bfloat16* __restrict__ outB,
    int M, int Nn, int K, int act, int vtmode) {
    __shared__ __align__(16) __hip_bfloat16 As[128 * 32];
    __shared__ __align__(16) __hip_bfloat16 Bs[128 * 32];
    int tid = threadIdx.x;
    int lane = tid & 63;
    int wave = tid >> 6;
    int col = lane & 15;
    int quad = lane >> 4;
    int bm = blockIdx.y * 128;
    int bn = blockIdx.x * 128;
    int wm = (wave & 1) * 64;
    int wn = (wave >> 1) * 64;
    f32x4 acc[4][4];
    #pragma unroll
    for (int i = 0; i < 4; ++i)
        #pragma unroll
        for (int j = 0; j < 4; ++j) acc[i][j] = (f32x4){0.f, 0.f, 0.f, 0.f};

    for (int k0 = 0; k0 < K; k0 += 32) {
        #pragma unroll
        for (int cc = 0; cc < 2; ++cc) {
            int c = tid + cc * 256;
            int gm = bm + (c >> 2); if (gm >= M) gm = M - 1;
            bf16x8 va = *(const bf16x8*)(const void*)(A + (size_t)gm * K + k0 + (c & 3) * 8);
            *(bf16x8*)(void*)&As[c * 8] = va;
            int gn = bn + (c >> 2); if (gn >= Nn) gn = Nn - 1;
            bf16x8 vb = *(const bf16x8*)(const void*)(Wt + (size_t)gn * K + k0 + (c & 3) * 8);
            *(bf16x8*)(void*)&Bs[c * 8] = vb;
        }
        __syncthreads();
        bf16x8 af[4], bf[4];
        #pragma unroll
        for (int i = 0; i < 4; ++i)
            af[i] = *(const bf16x8*)(const void*)&As[(wm + i * 16 + col) * 32 + quad * 8];
        #pragma unroll
        for (int j = 0; j < 4; ++j)
            bf[j] = *(const bf16x8*)(const void*)&Bs[(wn + j * 16 + col) * 32 + quad * 8];
        #pragma unroll
        for (int i = 0; i < 4; ++i)
            #pragma unroll
            for (int j = 0; j < 4; ++j)
                acc[i][j] = __builtin_amdgcn_mfma_f32_16x16x32_bf16(af[i], bf[j], acc[i][j], 0, 0, 0);
        __syncthreads();
    }
    #pragma unroll
    for (int i = 0; i < 4; ++i) {
        int gmb = bm + wm + i * 16 + quad * 4;
        #pragma unroll
        for (int j = 0; j < 4; ++j) {
            int gn = bn + wn + j * 16 + col;
            if (gn >= Nn) continue;
            float bs = bias[gn];
            #pragma unroll
            for (int r = 0; r < 4; ++r) {
                int gm = gmb + r;
                if (gm >= M) continue;
                float v = acc[i][j][r] + bs;
                if (act == 1) v = 0.5f * v * (1.f + erff(v * 0.70710678118654752f));
                if (res) v += res[(size_t)gm * Nn + gn];
                if (outF) outF[(size_t)gm * Nn + gn] = v;
                if (outB) {
                    if (vtmode) {
                        int bb = gm / T;
                        int tt = gm - bb * T;
                        outB[((size_t)bb * 512 + gn) * VTS + tt] = __float2bfloat16(v);
                    } else {
                        outB[(size_t)gm * Nn + gn] = __float2bfloat16(v);
                    }
                }
            }
        }
    }
}

// ---------- MFMA attention: 1 wave/block, 16 query rows per wave ----------
__global__ __launch_bounds__(64) void attn_mfma_kernel(
    const __hip_bfloat16* __restrict__ qb, const __hip_bfloat16* __restrict__ kb,
    const __hip_bfloat16* __restrict__ vt, const __hip_bfloat16* __restrict__ gd,
    __hip_bfloat16* __restrict__ ctxb) {
    __shared__ __align__(16) __hip_bfloat16 P[16][TPAD];
    int bid = blockIdx.x;
    int strip = bid % 33;
    int h = (bid / 33) % H;
    int b = bid / (33 * H);
    int q0 = strip * 16;
    int lane = threadIdx.x;
    int col = lane & 15;
    int quad = lane >> 4;

    int qr = q0 + col; if (qr > T - 1) qr = T - 1;
    const __hip_bfloat16* qptr = qb + (size_t)(b * T + qr) * D + h * E + quad * 8;
    bf16x8 a0 = *(const bf16x8*)(const void*)qptr;
    bf16x8 a1 = *(const bf16x8*)(const void*)(qptr + 32);

    f32x4 s[33];
    #pragma unroll
    for (int t = 0; t < 33; ++t) {
        int sr = t * 16 + col; if (sr > T - 1) sr = T - 1;
        const __hip_bfloat16* kptr = kb + (size_t)(b * T + sr) * D + h * E + quad * 8;
        bf16x8 b0 = *(const bf16x8*)(const void*)kptr;
        bf16x8 b1 = *(const bf16x8*)(const void*)(kptr + 32);
        f32x4 acc = (f32x4){0.f, 0.f, 0.f, 0.f};
        acc = __builtin_amdgcn_mfma_f32_16x16x32_bf16(a0, b0, acc, 0, 0, 0);
        acc = __builtin_amdgcn_mfma_f32_16x16x32_bf16(a1, b1, acc, 0, 0, 0);
        s[t] = acc;
    }
    float mx[4] = {-1e30f, -1e30f, -1e30f, -1e30f};
    #pragma unroll
    for (int t = 0; t < 33; ++t)
        #pragma unroll
        for (int r = 0; r < 4; ++r) {
            float v = s[t][r] * 0.125f;
            if (t * 16 + col >= T) v = -1e30f;
            s[t][r] = v;
            mx[r] = fmaxf(mx[r], v);
        }
    #pragma unroll
    for (int r = 0; r < 4; ++r)
        #pragma unroll
        for (int d = 1; d < 16; d <<= 1) mx[r] = fmaxf(mx[r], __shfl_xor(mx[r], d, 64));
    float sp[4] = {0.f, 0.f, 0.f, 0.f};
    #pragma unroll
    for (int t = 0; t < 33; ++t)
        #pragma unroll
        for (int r = 0; r < 4; ++r) {
            float p = __expf(s[t][r] - mx[r]);
            s[t][r] = p;
            sp[r] += p;
        }
    #pragma unroll
    for (int r = 0; r < 4; ++r)
        #pragma unroll
        for (int d = 1; d < 16; d <<= 1) sp[r] += __shfl_xor(sp[r], d, 64);
    float invsp[4];
    #pragma unroll
    for (int r = 0; r < 4; ++r) invsp[r] = 1.f / sp[r];
    float st[4] = {0.f, 0.f, 0.f, 0.f};
    #pragma unroll
    for (int t = 0; t < 33; ++t) {
        int sg = t * 16 + col;
        #pragma unroll
        for (int r = 0; r < 4; ++r) {
            int lrow = q0 + quad * 4 + r;
            float g = 0.5f;
            if (lrow < N && sg < N)
                g = __bfloat162float(gd[((size_t)b * N + lrow) * N + sg]);
            float tv = s[t][r] * invsp[r] * g;
            s[t][r] = tv;
            st[r] += tv;
        }
    }
    #pragma unroll
    for (int r = 0; r < 4; ++r)
        #pragma unroll
        for (int d = 1; d < 16; d <<= 1) st[r] += __shfl_xor(st[r], d, 64);
    float inv[4];
    #pragma unroll
    for (int r = 0; r < 4; ++r) inv[r] = 1.f / (st[r] + 1e-6f);
    #pragma unroll
    for (int t = 0; t < 33; ++t)
        #pragma unroll
        for (int r = 0; r < 4; ++r)
            P[quad * 4 + r][t * 16 + col] = __float2bfloat16(s[t][r]);
    #pragma unroll
    for (int r = 0; r < 4; ++r)
        P[quad * 4 + r][528 + col] = __float2bfloat16(0.f);
    f32x4 o[4];
    #pragma unroll
    for (int j = 0; j < 4; ++j) o[j] = (f32x4){0.f, 0.f, 0.f, 0.f};
    const __hip_bfloat16* vbase = vt + (size_t)((b * H + h) * E) * VTS;
    #pragma unroll
    for (int ks = 0; ks < 17; ++ks) {
        bf16x8 pa = *(const bf16x8*)(const void*)&P[col][ks * 32 + quad * 8];
        #pragma unroll
        for (int j = 0; j < 4; ++j) {
            bf16x8 bv = *(const bf16x8*)(const void*)
                (vbase + (size_t)(j * 16 + col) * VTS + ks * 32 + quad * 8);
            o[j] = __builtin_amdgcn_mfma_f32_16x16x32_bf16(pa, bv, o[j], 0, 0, 0);
        }
    }
    #pragma unroll
    for (int j = 0; j < 4; ++j)
        #pragma unroll
        for (int r = 0; r < 4; ++r) {
            int row = q0 + quad * 4 + r;
            if (row < T)
                ctxb[(size_t)(b * T + row) * D + h * E + j * 16 + col] =
                    __float2bfloat16(o[j][r] * inv[r]);
        }
}

// ---------- layernorm over D per row: f32 in -> f32 out + bf16 shadow ----------
__global__ void ln_kernel(const float* __restrict__ in, const float* __restrict__ g,
                          const float* __restrict__ bb, float* __restrict__ outF,
                          __hip_bfloat16* __restrict__ outB) {
    int row = blockIdx.x;
    int tid = threadIdx.x;
    __shared__ float red[256];
    float v0 = in[(size_t)row * D + tid];
    float v1 = in[(size_t)row * D + 256 + tid];
    float s = block_reduce_sum256(v0 + v1, red);
    float ss = block_reduce_sum256(v0 * v0 + v1 * v1, red);
    float m = s / (float)D;
    float var = ss / (float)D - m * m;
    float rstd = rsqrtf(fmaxf(var, 0.f) + 1e-5f);
    float o0 = (v0 - m) * rstd * g[tid] + bb[tid];
    float o1 = (v1 - m) * rstd * g[256 + tid] + bb[256 + tid];
    outF[(size_t)row * D + tid] = o0;
    outF[(size_t)row * D + 256 + tid] = o1;
    outB[(size_t)row * D + tid] = __float2bfloat16(o0);
    outB[(size_t)row * D + 256 + tid] = __float2bfloat16(o1);
}

// ---------- final: transpose + RevIN inverse ----------
__global__ void revin_inv_kernel(const float* __restrict__ dec, const float* __restrict__ beta,
                                 const float* __restrict__ gamma, const float* __restrict__ mean,
                                 const float* __restrict__ stdv, float* __restrict__ out) {
    int idx = blockIdx.x * blockDim.x + threadIdx.x;
    if (idx >= B * PRED * N) return;
    int n = idx % N;
    int p = (idx / N) % PRED;
    int b = idx / (N * PRED);
    float v = dec[((size_t)b * T + n) * PRED + p];
    int bn = b * N + n;
    out[idx] = (v - beta[n]) / (gamma[n] + 1e-5f) * stdv[bn] + mean[bn];
}

extern "C" void kernel_launch(void* const* d_in, const int* in_sizes, int n_in,
                              void* d_out, int out_size, void* d_ws, size_t ws_size,
                              hipStream_t stream) {
    const float* x_enc  = (const float*)d_in[0];
    const float* x_mark = (const float*)d_in[1];
    const float* gamma  = (const float*)d_in[4];
    const float* beta   = (const float*)d_in[5];
    const float* tp_w1  = (const float*)d_in[6];
    const float* tp_b1  = (const float*)d_in[7];
    const float* tp_w2  = (const float*)d_in[8];
    const float* tp_b2  = (const float*)d_in[9];
    const float* emb_w  = (const float*)d_in[10];
    const float* emb_b  = (const float*)d_in[11];
    const float* wq = (const float*)d_in[12];
    const float* bq = (const float*)d_in[13];
    const float* wk = (const float*)d_in[14];
    const float* bk = (const float*)d_in[15];
    const float* wv = (const float*)d_in[16];
    const float* bv = (const float*)d_in[17];
    const float* wo = (const float*)d_in[18];
    const float* bo = (const float*)d_in[19];
    const float* w1 = (const float*)d_in[20];
    const float* b1 = (const float*)d_in[21];
    const float* w2 = (const float*)d_in[22];
    const float* b2 = (const float*)d_in[23];
    const float* ln1g = (const float*)d_in[24];
    const float* ln1b = (const float*)d_in[25];
    const float* ln2g = (const float*)d_in[26];
    const float* ln2b = (const float*)d_in[27];
    const float* normg = (const float*)d_in[28];
    const float* normb = (const float*)d_in[29];
    const float* proj_w = (const float*)d_in[30];
    const float* proj_b = (const float*)d_in[31];

    char* ws = (char*)d_ws;
    float* mean = (float*)(ws + WS_MEAN);
    float* stdv = (float*)(ws + WS_STD);
    __hip_bfloat16* gd  = (__hip_bfloat16*)(ws + WS_GD);
    float* x            = (float*)(ws + WS_X);
    __hip_bfloat16* xb  = (__hip_bfloat16*)(ws + WS_XB);
    __hip_bfloat16* wts = (__hip_bfloat16*)(ws + WS_WTS);
    __hip_bfloat16* qbuf = (__hip_bfloat16*)(ws + WS_QB);
    __hip_bfloat16* kbuf = (__hip_bfloat16*)(ws + WS_KB);
    __hip_bfloat16* vt   = (__hip_bfloat16*)(ws + WS_VT);
    float* xt  = (float*)(ws + WS_KB);
    float* nt  = (float*)(ws + WS_VT);
    __hip_bfloat16* tokb = (__hip_bfloat16*)(ws + WS_QB);
    __hip_bfloat16* ctxb = xb;
    __hip_bfloat16* ffnb = (__hip_bfloat16*)(ws + WS_QB);
    float* dec = (float*)(ws + WS_QB);

    revin_stats_kernel<<<(B * N + 255) / 256, 256, 0, stream>>>(x_enc, mean, stdv);
    norm_transpose_kernel<<<(B * N * L + 255) / 256, 256, 0, stream>>>(x_enc, mean, stdv, gamma, beta, xt);
    trend_nt_kernel<<<B * N, 128, 0, stream>>>(xt, tp_w1, tp_b1, tp_w2, tp_b2, nt);
    guide_kernel<<<dim3(N / 16, N / 16, B), dim3(16, 16), 0, stream>>>(nt, gd);
    // vt aliases nt: stale nt bytes reinterpreted as bf16 can be NaN/Inf in the
    // never-written pad tokens 516..527; 0 * NaN = NaN in the PV MFMA. Zero vt
    // once per launch (layer 1 rewrites tokens 0..515 only; pads stay 0).
    hipMemsetAsync(vt, 0, VT_BYTES, stream);
    build_tok_kernel<<<(B * T * L + 255) / 256, 256, 0, stream>>>(xt, x_mark, tokb);
    wconv_kernel<<<6240, 256, 0, stream>>>(wq, wk, wv, wo, w1, w2, emb_w, proj_w, wts);

    const int M = B * T;                   // 8256
    const int MT = (M + 127) / 128;        // 65
    mfma_gemm<<<dim3(D / 128, MT), 256, 0, stream>>>(tokb, wts + WT_EMB, emb_b, nullptr,
                                                     x, xb, M, D, L, 0, 0);
    for (int i = 0; i < 2; ++i) {
        const __hip_bfloat16* wqT = wts + WT_WQ + (size_t)i * D * D;
        const __hip_bfloat16* wkT = wts + WT_WK + (size_t)i * D * D;
        const __hip_bfloat16* wvT = wts + WT_WV + (size_t)i * D * D;
        const __hip_bfloat16* woT = wts + WT_WO + (size_t)i * D * D;
        mfma_gemm<<<dim3(D / 128, MT), 256, 0, stream>>>(xb, wqT, bq + i * D, nullptr,
                                                         nullptr, qbuf, M, D, D, 0, 0);
        mfma_gemm<<<dim3(D / 128, MT), 256, 0, stream>>>(xb, wkT, bk + i * D, nullptr,
                                                         nullptr, kbuf, M, D, D, 0, 0);
        mfma_gemm<<<dim3(D / 128, MT), 256, 0, stream>>>(xb, wvT, bv + i * D, nullptr,
                                                         nullptr, vt, M, D, D, 0, 1);
        attn_mfma_kernel<<<B * H * 33, 64, 0, stream>>>(qbuf, kbuf, vt, gd, ctxb);
        mfma_gemm<<<dim3(D / 128, MT), 256, 0, stream>>>(ctxb, woT, bo + i * D, x,
                                                         x, nullptr, M, D, D, 0, 0);
        ln_kernel<<<M, 256, 0, stream>>>(x, ln1g + i * D, ln1b + i * D, x, xb);
        mfma_gemm<<<dim3(DFF / 128, MT), 256, 0, stream>>>(xb, wts + WT_W1 + (size_t)i * DFF * D,
                                                           b1 + i * DFF, nullptr,
                                                           nullptr, ffnb, M, DFF, D, 1, 0);
        mfma_gemm<<<dim3(D / 128, MT), 256, 0, stream>>>(ffnb, wts + WT_W2 + (size_t)i * DFF * D,
                                                         b2 + i * D, x, x, nullptr, M, D, DFF, 0, 0);
        ln_kernel<<<M, 256, 0, stream>>>(x, ln2g + i * D, ln2b + i * D, x, xb);
    }
    ln_kernel<<<M, 256, 0, stream>>>(x, normg, normb, x, xb);
    mfma_gemm<<<dim3(1, MT), 256, 0, stream>>>(xb, wts + WT_PROJ, proj_b, nullptr,
                                               dec, nullptr, M, PRED, D, 0, 0);
    revin_inv_kernel<<<(B * PRED * N + 255) / 256, 256, 0, stream>>>(dec, beta, gamma, mean, stdv,
                                                                     (float*)d_out);
}

// Round 5
// 1051.754 us; speedup vs baseline: 7.8012x; 1.3134x over previous
//
#include <hip/hip_runtime.h>
#include <hip/hip_bf16.h>
#include <math.h>

#define B 16
#define L 96
#define N 512
#define D 512
#define H 8
#define E 64
#define DFF 2048
#define T 516
#define PRED 96
#define NMARK 4
#define VTS 576    // vt row stride (keys, padded from 516 to 9*64)
#define NCHUNK 9   // key chunks of 64

typedef __attribute__((ext_vector_type(8))) short bf16x8;
typedef __attribute__((ext_vector_type(4))) float f32x4;

// ---- workspace layout (BYTE offsets). Total 80,412,672 B ----
#define WS_MEAN 0              // f32 [B,N]
#define WS_STD  32768          // f32 [B,N]
#define WS_GD   65536          // bf16 [B,N,N] = 8,388,608 B
#define WS_X    8454144        // f32 [B,T,D] = 16,908,288 B (residual master)
#define WS_XB   25362432       // bf16 [B,T,D] (bf16 shadow; also ctxb)
#define WS_WTS  33816576       // bf16 transposed weights, 12,779,520 B
#define WS_QB   46596096       // bf16 [B,T,D]; also tokb(bf16), dec(f32), ffn base
#define WS_KB   55050240       // bf16 [B,T,D]; also xt(f32)
#define WS_VT   63504384       // bf16 [B,H,64,VTS] = 9,437,184 B (ends 72,941,568); also nt(f32)
#define VT_BYTES 9437184
// ffnb = WS_QB .. WS_QB + 8256*2048*2 = 80,412,672 (spans qb,kb,vt; time-disjoint)

// weight-arena element offsets (bf16 elements from WS_WTS)
#define WT_WQ   0u
#define WT_WK   524288u
#define WT_WV   1048576u
#define WT_WO   1572864u
#define WT_W1   2097152u
#define WT_W2   4194304u
#define WT_EMB  6291456u
#define WT_PROJ 6340608u

__device__ __forceinline__ float block_reduce_sum256(float v, float* red) {
    int tid = threadIdx.x;
    red[tid] = v; __syncthreads();
    for (int off = 128; off > 0; off >>= 1) {
        if (tid < off) red[tid] += red[tid + off];
        __syncthreads();
    }
    float r = red[0];
    __syncthreads();
    return r;
}

// ---------- RevIN stats ----------
__global__ void revin_stats_kernel(const float* __restrict__ x, float* __restrict__ mean,
                                   float* __restrict__ stdv) {
    int i = blockIdx.x * blockDim.x + threadIdx.x;
    if (i >= B * N) return;
    int b = i >> 9;
    int n = i & (N - 1);
    const float* p = x + (size_t)b * L * N + n;
    float s = 0.f, ss = 0.f;
    for (int l = 0; l < L; ++l) {
        float v = p[(size_t)l * N];
        s += v; ss += v * v;
    }
    float m = s / (float)L;
    float var = ss / (float)L - m * m;
    mean[i] = m;
    stdv[i] = sqrtf(fmaxf(var, 0.f) + 1e-5f);
}

// ---------- normalize + transpose: xt[b,n,l] (f32) ----------
__global__ void norm_transpose_kernel(const float* __restrict__ x, const float* __restrict__ mean,
                                      const float* __restrict__ stdv, const float* __restrict__ gamma,
                                      const float* __restrict__ beta, float* __restrict__ xt) {
    int idx = blockIdx.x * blockDim.x + threadIdx.x;
    if (idx >= B * N * L) return;
    int l = idx % L;
    int n = (idx / L) % N;
    int b = idx / (L * N);
    float v = x[((size_t)b * L + l) * N + n];
    int bn = b * N + n;
    xt[idx] = (v - mean[bn]) / stdv[bn] * gamma[n] + beta[n];
}

// ---------- trend + normalized trend rows nt[b,n,l] (f32) ----------
__global__ void trend_nt_kernel(const float* __restrict__ xt, const float* __restrict__ tp_w1,
                                const float* __restrict__ tp_b1, const float* __restrict__ tp_w2,
                                const float* __restrict__ tp_b2, float* __restrict__ nt) {
    int bn = blockIdx.x;
    __shared__ float xr[96];
    __shared__ float P[97];
    __shared__ float wt[4];
    __shared__ float tr[96];
    __shared__ float nrm;
    int tid = threadIdx.x;
    if (tid < 96) xr[tid] = xt[(size_t)bn * 96 + tid];
    __syncthreads();
    if (tid == 0) {
        float s = 0.f, ss = 0.f;
        P[0] = 0.f;
        for (int l = 0; l < 96; ++l) { s += xr[l]; P[l + 1] = s; ss += xr[l] * xr[l]; }
        float m = s / 96.f;
        float var = ss / 96.f - m * m;
        float sd = sqrtf(fmaxf(var, 0.f) + 1e-6f);
        float h[16];
        for (int j = 0; j < 16; ++j) {
            float t = m * tp_w1[j] + sd * tp_w1[16 + j] + tp_b1[j];
            h[j] = fmaxf(t, 0.f);
        }
        float lg[4];
        for (int w = 0; w < 4; ++w) {
            float t = tp_b2[w];
            for (int j = 0; j < 16; ++j) t += h[j] * tp_w2[j * 4 + w];
            lg[w] = t;
        }
        float mx = fmaxf(fmaxf(lg[0], lg[1]), fmaxf(lg[2], lg[3]));
        float es = 0.f;
        for (int w = 0; w < 4; ++w) { lg[w] = expf(lg[w] - mx); es += lg[w]; }
        for (int w = 0; w < 4; ++w) wt[w] = lg[w] / es;
    }
    __syncthreads();
    const int WS[4] = {4, 8, 12, 24};
    if (tid < 96) {
        int l = tid;
        float t = 0.f;
        for (int wi = 0; wi < 4; ++wi) {
            int w = WS[wi];
            int lo = l - w + 1;
            float s;
            if (lo >= 0) s = P[l + 1] - P[lo];
            else         s = P[l + 1] - P[0] + (float)(-lo) * xr[0];
            t += (s / (float)w) * wt[wi];
        }
        tr[l] = t;
    }
    __syncthreads();
    if (tid == 0) {
        float s = 0.f;
        for (int l = 0; l < 96; ++l) s += tr[l] * tr[l];
        nrm = fmaxf(sqrtf(s), 1e-12f);
    }
    __syncthreads();
    if (tid < 96) nt[(size_t)bn * 96 + tid] = tr[tid] / nrm;
}

// ---------- guidance: sigmoid(nt @ nt^T) -> bf16 ----------
__global__ void guide_kernel(const float* __restrict__ nt, __hip_bfloat16* __restrict__ guide) {
    __shared__ float ri[16][97];
    __shared__ float rj[16][97];
    int b = blockIdx.z;
    int i0 = blockIdx.y * 16;
    int j0 = blockIdx.x * 16;
    int tx = threadIdx.x, ty = threadIdx.y;
    int tid = ty * 16 + tx;
    for (int t = tid; t < 16 * 96; t += 256) {
        int r = t / 96, c = t % 96;
        ri[r][c] = nt[((size_t)b * N + i0 + r) * 96 + c];
        rj[r][c] = nt[((size_t)b * N + j0 + r) * 96 + c];
    }
    __syncthreads();
    float acc = 0.f;
    for (int k = 0; k < 96; ++k) acc += ri[ty][k] * rj[tx][k];
    guide[((size_t)b * N + i0 + ty) * N + j0 + tx] =
        __float2bfloat16(1.f / (1.f + expf(-acc)));
}

// ---------- build tokens [B,T,L] bf16 ----------
__global__ void build_tok_kernel(const float* __restrict__ xt, const float* __restrict__ xmark,
                                 __hip_bfloat16* __restrict__ tok) {
    int idx = blockIdx.x * blockDim.x + threadIdx.x;
    if (idx >= B * T * L) return;
    int l = idx % L;
    int t = (idx / L) % T;
    int b = idx / (L * T);
    float v;
    if (t < N) v = xt[((size_t)b * N + t) * L + l];
    else       v = xmark[((size_t)b * L + l) * NMARK + (t - N)];
    tok[idx] = __float2bfloat16(v);
}

// ---------- weight transpose+convert: fp32 [K,N] -> bf16 [N,K] ----------
__global__ void wconv_kernel(const float* __restrict__ wq, const float* __restrict__ wk,
                             const float* __restrict__ wv, const float* __restrict__ wo,
                             const float* __restrict__ w1, const float* __restrict__ w2,
                             const float* __restrict__ emb, const float* __restrict__ proj,
                             __hip_bfloat16* __restrict__ wts) {
    int bid = blockIdx.x;
    const float* src; __hip_bfloat16* dst; int K, Nn, tloc;
    if (bid < 2048) {
        int seg = bid >> 9;
        int t = bid & 511;
        int layer = t >> 8;
        tloc = t & 255;
        K = 512; Nn = 512;
        const float* bases[4] = {wq, wk, wv, wo};
        src = bases[seg] + (size_t)layer * 512 * 512;
        dst = wts + (seg == 0 ? WT_WQ : seg == 1 ? WT_WK : seg == 2 ? WT_WV : WT_WO)
                  + (size_t)layer * 512 * 512;
    } else if (bid < 4096) {
        int t = bid - 2048;
        int layer = t >> 10;
        tloc = t & 1023;
        K = 512; Nn = 2048;
        src = w1 + (size_t)layer * 512 * 2048;
        dst = wts + WT_W1 + (size_t)layer * 2048 * 512;
    } else if (bid < 6144) {
        int t = bid - 4096;
        int layer = t >> 10;
        tloc = t & 1023;
        K = 2048; Nn = 512;
        src = w2 + (size_t)layer * 2048 * 512;
        dst = wts + WT_W2 + (size_t)layer * 512 * 2048;
    } else if (bid < 6192) {
        tloc = bid - 6144;
        K = 96; Nn = 512;
        src = emb; dst = wts + WT_EMB;
    } else {
        tloc = bid - 6192;
        K = 512; Nn = 96;
        src = proj; dst = wts + WT_PROJ;
    }
    int ntile = Nn >> 5;
    int tk = tloc / ntile, tn = tloc % ntile;
    int k0 = tk * 32, n0 = tn * 32;
    __shared__ float ld[32][33];
    int tid = threadIdx.x;
    for (int i = tid; i < 1024; i += 256) {
        int r = i >> 5, c = i & 31;
        ld[r][c] = src[(size_t)(k0 + r) * Nn + n0 + c];
    }
    __syncthreads();
    for (int i = tid; i < 1024; i += 256) {
        int r = i >> 5, c = i & 31;
        dst[(size_t)(n0 + r) * K + k0 + c] = __float2bfloat16(ld[c][r]);
    }
}

// ---------- MFMA bf16 GEMM: 128x128 tile, BK=32, 4 waves ----------
__global__ __launch_bounds__(256, 2) void mfma_gemm(
    const __hip_bfloat16* __restrict__ A, const __hip_bfloat16* __restrict__ Wt,
    const float* __restrict__ bias, const float* __restrict__ res,
    float* __restrict__ outF, __hip_bfloat16* __restrict__ outB,
    int M, int Nn, int K, int act, int vtmode) {
    __shared__ __align__(16) __hip_bfloat16 As[128 * 32];
    __shared__ __align__(16) __hip_bfloat16 Bs[128 * 32];
    int tid = threadIdx.x;
    int lane = tid & 63;
    int wave = tid >> 6;
    int col = lane & 15;
    int quad = lane >> 4;
    int bm = blockIdx.y * 128;
    int bn = blockIdx.x * 128;
    int wm = (wave & 1) * 64;
    int wn = (wave >> 1) * 64;
    f32x4 acc[4][4];
    #pragma unroll
    for (int i = 0; i < 4; ++i)
        #pragma unroll
        for (int j = 0; j < 4; ++j) acc[i][j] = (f32x4){0.f, 0.f, 0.f, 0.f};

    for (int k0 = 0; k0 < K; k0 += 32) {
        #pragma unroll
        for (int cc = 0; cc < 2; ++cc) {
            int c = tid + cc * 256;
            int gm = bm + (c >> 2); if (gm >= M) gm = M - 1;
            bf16x8 va = *(const bf16x8*)(const void*)(A + (size_t)gm * K + k0 + (c & 3) * 8);
            *(bf16x8*)(void*)&As[c * 8] = va;
            int gn = bn + (c >> 2); if (gn >= Nn) gn = Nn - 1;
            bf16x8 vb = *(const bf16x8*)(const void*)(Wt + (size_t)gn * K + k0 + (c & 3) * 8);
            *(bf16x8*)(void*)&Bs[c * 8] = vb;
        }
        __syncthreads();
        bf16x8 af[4], bf[4];
        #pragma unroll
        for (int i = 0; i < 4; ++i)
            af[i] = *(const bf16x8*)(const void*)&As[(wm + i * 16 + col) * 32 + quad * 8];
        #pragma unroll
        for (int j = 0; j < 4; ++j)
            bf[j] = *(const bf16x8*)(const void*)&Bs[(wn + j * 16 + col) * 32 + quad * 8];
        #pragma unroll
        for (int i = 0; i < 4; ++i)
            #pragma unroll
            for (int j = 0; j < 4; ++j)
                acc[i][j] = __builtin_amdgcn_mfma_f32_16x16x32_bf16(af[i], bf[j], acc[i][j], 0, 0, 0);
        __syncthreads();
    }
    #pragma unroll
    for (int i = 0; i < 4; ++i) {
        int gmb = bm + wm + i * 16 + quad * 4;
        #pragma unroll
        for (int j = 0; j < 4; ++j) {
            int gn = bn + wn + j * 16 + col;
            if (gn >= Nn) continue;
            float bs = bias[gn];
            #pragma unroll
            for (int r = 0; r < 4; ++r) {
                int gm = gmb + r;
                if (gm >= M) continue;
                float v = acc[i][j][r] + bs;
                if (act == 1) v = 0.5f * v * (1.f + erff(v * 0.70710678118654752f));
                if (res) v += res[(size_t)gm * Nn + gn];
                if (outF) outF[(size_t)gm * Nn + gn] = v;
                if (outB) {
                    if (vtmode) {
                        int bb = gm / T;
                        int tt = gm - bb * T;
                        outB[((size_t)bb * 512 + gn) * VTS + tt] = __float2bfloat16(v);
                    } else {
                        outB[(size_t)gm * Nn + gn] = __float2bfloat16(v);
                    }
                }
            }
        }
    }
}

// ---------- flash-style MFMA attention ----------
// Block = 256 threads = 4 waves, each wave owns 16 query rows (block: 64 rows).
// Grid = B*H*9. Online accumulation over 9 chunks of 64 keys:
//   p~ = exp(s - m); S = sum p~; G = sum p~*g; A = sum p~*g*v (MFMA, rescaled)
//   out = A / (G + 1e-6*S)   [exact algebraic fold of softmax+gate+renorm]
__global__ __launch_bounds__(256) void attn_flash_kernel(
    const __hip_bfloat16* __restrict__ qb, const __hip_bfloat16* __restrict__ kb,
    const __hip_bfloat16* __restrict__ vt, const __hip_bfloat16* __restrict__ gd,
    __hip_bfloat16* __restrict__ ctxb) {
    __shared__ __align__(16) __hip_bfloat16 Ks[64][72];   // keys x E (+8 pad: 2-way banks)
    __shared__ __align__(16) __hip_bfloat16 Vs[64][72];   // E x keys (V^T tile)
    __shared__ __align__(16) __hip_bfloat16 Pw[4][16][72]; // per-wave P tile
    int bid = blockIdx.x;
    int sg = bid % 9;
    int h = (bid / 9) % H;
    int b = bid / (9 * H);
    int tid = threadIdx.x;
    int wave = tid >> 6, lane = tid & 63;
    int col = lane & 15, quad = lane >> 4;
    int q0 = sg * 64 + wave * 16;

    // Q A-frags (m=lane&15, k=quad*8+j), rows clamped (invalid rows not stored)
    int qr = q0 + col; if (qr > T - 1) qr = T - 1;
    const __hip_bfloat16* qptr = qb + (size_t)(b * T + qr) * D + h * E + quad * 8;
    bf16x8 a0 = *(const bf16x8*)(const void*)qptr;
    bf16x8 a1 = *(const bf16x8*)(const void*)(qptr + 32);

    float m_r[4] = {-1e30f, -1e30f, -1e30f, -1e30f};
    float S[4] = {0.f, 0.f, 0.f, 0.f};
    float G[4] = {0.f, 0.f, 0.f, 0.f};
    f32x4 o[4];
    #pragma unroll
    for (int j = 0; j < 4; ++j) o[j] = (f32x4){0.f, 0.f, 0.f, 0.f};

    const __hip_bfloat16* vbase = vt + (size_t)((b * H + h) * E) * VTS;

    for (int kc = 0; kc < NCHUNK; ++kc) {
        __syncthreads();   // protect Ks/Vs vs previous iteration's readers
        // cooperative stage: K chunk (64 keys x 64 E) and V^T chunk (64 E x 64 keys)
        #pragma unroll
        for (int i = 0; i < 2; ++i) {
            int idx = tid + i * 256;        // 0..511
            int r = idx >> 3, s = idx & 7;  // row 0..63, 16B-seg 0..7
            int kr = kc * 64 + r; int krc = kr > T - 1 ? T - 1 : kr;
            *(bf16x8*)(void*)&Ks[r][s * 8] =
                *(const bf16x8*)(const void*)(kb + (size_t)(b * T + krc) * D + h * E + s * 8);
            *(bf16x8*)(void*)&Vs[r][s * 8] =
                *(const bf16x8*)(const void*)(vbase + (size_t)r * VTS + kc * 64 + s * 8);
        }
        __syncthreads();
        // QK^T: 4 subtiles of 16 keys (K-dim 64 = 2 MFMAs)
        f32x4 sc[4];
        #pragma unroll
        for (int sub = 0; sub < 4; ++sub) {
            bf16x8 b0 = *(const bf16x8*)(const void*)&Ks[sub * 16 + col][quad * 8];
            bf16x8 b1 = *(const bf16x8*)(const void*)&Ks[sub * 16 + col][32 + quad * 8];
            f32x4 acc = (f32x4){0.f, 0.f, 0.f, 0.f};
            acc = __builtin_amdgcn_mfma_f32_16x16x32_bf16(a0, b0, acc, 0, 0, 0);
            acc = __builtin_amdgcn_mfma_f32_16x16x32_bf16(a1, b1, acc, 0, 0, 0);
            sc[sub] = acc;
        }
        // scale + mask; chunk row-max
        float cm[4] = {-1e30f, -1e30f, -1e30f, -1e30f};
        #pragma unroll
        for (int sub = 0; sub < 4; ++sub) {
            int key = kc * 64 + sub * 16 + col;
            #pragma unroll
            for (int r = 0; r < 4; ++r) {
                float v = sc[sub][r] * 0.125f;
                if (key >= T) v = -1e30f;
                sc[sub][r] = v;
                cm[r] = fmaxf(cm[r], v);
            }
        }
        #pragma unroll
        for (int r = 0; r < 4; ++r)
            #pragma unroll
            for (int d = 1; d < 16; d <<= 1) cm[r] = fmaxf(cm[r], __shfl_xor(cm[r], d, 64));
        // online rescale
        float alpha[4];
        #pragma unroll
        for (int r = 0; r < 4; ++r) {
            float mn = fmaxf(m_r[r], cm[r]);
            alpha[r] = __expf(m_r[r] - mn);
            m_r[r] = mn;
            S[r] *= alpha[r];
            G[r] *= alpha[r];
        }
        #pragma unroll
        for (int j = 0; j < 4; ++j)
            #pragma unroll
            for (int r = 0; r < 4; ++r) o[j][r] *= alpha[r];
        // p~, guide gate, accumulate, write P tile
        #pragma unroll
        for (int sub = 0; sub < 4; ++sub) {
            int key = kc * 64 + sub * 16 + col;
            #pragma unroll
            for (int r = 0; r < 4; ++r) {
                float p = __expf(sc[sub][r] - m_r[r]);   // masked -> exactly 0
                S[r] += p;
                int lrow = q0 + quad * 4 + r;
                float g = 0.5f;
                if (lrow < N && key < N)
                    g = __bfloat162float(gd[((size_t)b * N + lrow) * N + key]);
                float t = p * g;
                G[r] += t;
                Pw[wave][quad * 4 + r][sub * 16 + col] = __float2bfloat16(t);
            }
        }
        // PV: o += P(16x64) @ V(64x64); wave-local LDS (compiler orders ds ops)
        #pragma unroll
        for (int ks = 0; ks < 2; ++ks) {
            bf16x8 pa = *(const bf16x8*)(const void*)&Pw[wave][col][ks * 32 + quad * 8];
            #pragma unroll
            for (int j = 0; j < 4; ++j) {
                bf16x8 bv = *(const bf16x8*)(const void*)&Vs[j * 16 + col][ks * 32 + quad * 8];
                o[j] = __builtin_amdgcn_mfma_f32_16x16x32_bf16(pa, bv, o[j], 0, 0, 0);
            }
        }
    }
    // reduce S,G across the 16 lanes of each quad-row; final normalize
    #pragma unroll
    for (int r = 0; r < 4; ++r) {
        #pragma unroll
        for (int d = 1; d < 16; d <<= 1) {
            S[r] += __shfl_xor(S[r], d, 64);
            G[r] += __shfl_xor(G[r], d, 64);
        }
    }
    float inv[4];
    #pragma unroll
    for (int r = 0; r < 4; ++r) inv[r] = 1.f / (G[r] + 1e-6f * S[r]);
    #pragma unroll
    for (int j = 0; j < 4; ++j)
        #pragma unroll
        for (int r = 0; r < 4; ++r) {
            int row = q0 + quad * 4 + r;
            if (row < T)
                ctxb[(size_t)(b * T + row) * D + h * E + j * 16 + col] =
                    __float2bfloat16(o[j][r] * inv[r]);
        }
}

// ---------- layernorm over D per row: f32 in -> f32 out + bf16 shadow ----------
__global__ void ln_kernel(const float* __restrict__ in, const float* __restrict__ g,
                          const float* __restrict__ bb, float* __restrict__ outF,
                          __hip_bfloat16* __restrict__ outB) {
    int row = blockIdx.x;
    int tid = threadIdx.x;
    __shared__ float red[256];
    float v0 = in[(size_t)row * D + tid];
    float v1 = in[(size_t)row * D + 256 + tid];
    float s = block_reduce_sum256(v0 + v1, red);
    float ss = block_reduce_sum256(v0 * v0 + v1 * v1, red);
    float m = s / (float)D;
    float var = ss / (float)D - m * m;
    float rstd = rsqrtf(fmaxf(var, 0.f) + 1e-5f);
    float o0 = (v0 - m) * rstd * g[tid] + bb[tid];
    float o1 = (v1 - m) * rstd * g[256 + tid] + bb[256 + tid];
    outF[(size_t)row * D + tid] = o0;
    outF[(size_t)row * D + 256 + tid] = o1;
    outB[(size_t)row * D + tid] = __float2bfloat16(o0);
    outB[(size_t)row * D + 256 + tid] = __float2bfloat16(o1);
}

// ---------- final: transpose + RevIN inverse ----------
__global__ void revin_inv_kernel(const float* __restrict__ dec, const float* __restrict__ beta,
                                 const float* __restrict__ gamma, const float* __restrict__ mean,
                                 const float* __restrict__ stdv, float* __restrict__ out) {
    int idx = blockIdx.x * blockDim.x + threadIdx.x;
    if (idx >= B * PRED * N) return;
    int n = idx % N;
    int p = (idx / N) % PRED;
    int b = idx / (N * PRED);
    float v = dec[((size_t)b * T + n) * PRED + p];
    int bn = b * N + n;
    out[idx] = (v - beta[n]) / (gamma[n] + 1e-5f) * stdv[bn] + mean[bn];
}

extern "C" void kernel_launch(void* const* d_in, const int* in_sizes, int n_in,
                              void* d_out, int out_size, void* d_ws, size_t ws_size,
                              hipStream_t stream) {
    const float* x_enc  = (const float*)d_in[0];
    const float* x_mark = (const float*)d_in[1];
    const float* gamma  = (const float*)d_in[4];
    const float* beta   = (const float*)d_in[5];
    const float* tp_w1  = (const float*)d_in[6];
    const float* tp_b1  = (const float*)d_in[7];
    const float* tp_w2  = (const float*)d_in[8];
    const float* tp_b2  = (const float*)d_in[9];
    const float* emb_w  = (const float*)d_in[10];
    const float* emb_b  = (const float*)d_in[11];
    const float* wq = (const float*)d_in[12];
    const float* bq = (const float*)d_in[13];
    const float* wk = (const float*)d_in[14];
    const float* bk = (const float*)d_in[15];
    const float* wv = (const float*)d_in[16];
    const float* bv = (const float*)d_in[17];
    const float* wo = (const float*)d_in[18];
    const float* bo = (const float*)d_in[19];
    const float* w1 = (const float*)d_in[20];
    const float* b1 = (const float*)d_in[21];
    const float* w2 = (const float*)d_in[22];
    const float* b2 = (const float*)d_in[23];
    const float* ln1g = (const float*)d_in[24];
    const float* ln1b = (const float*)d_in[25];
    const float* ln2g = (const float*)d_in[26];
    const float* ln2b = (const float*)d_in[27];
    const float* normg = (const float*)d_in[28];
    const float* normb = (const float*)d_in[29];
    const float* proj_w = (const float*)d_in[30];
    const float* proj_b = (const float*)d_in[31];

    char* ws = (char*)d_ws;
    float* mean = (float*)(ws + WS_MEAN);
    float* stdv = (float*)(ws + WS_STD);
    __hip_bfloat16* gd  = (__hip_bfloat16*)(ws + WS_GD);
    float* x            = (float*)(ws + WS_X);
    __hip_bfloat16* xb  = (__hip_bfloat16*)(ws + WS_XB);
    __hip_bfloat16* wts = (__hip_bfloat16*)(ws + WS_WTS);
    __hip_bfloat16* qbuf = (__hip_bfloat16*)(ws + WS_QB);
    __hip_bfloat16* kbuf = (__hip_bfloat16*)(ws + WS_KB);
    __hip_bfloat16* vt   = (__hip_bfloat16*)(ws + WS_VT);
    float* xt  = (float*)(ws + WS_KB);
    float* nt  = (float*)(ws + WS_VT);
    __hip_bfloat16* tokb = (__hip_bfloat16*)(ws + WS_QB);
    __hip_bfloat16* ctxb = xb;
    __hip_bfloat16* ffnb = (__hip_bfloat16*)(ws + WS_QB);
    float* dec = (float*)(ws + WS_QB);

    revin_stats_kernel<<<(B * N + 255) / 256, 256, 0, stream>>>(x_enc, mean, stdv);
    norm_transpose_kernel<<<(B * N * L + 255) / 256, 256, 0, stream>>>(x_enc, mean, stdv, gamma, beta, xt);
    trend_nt_kernel<<<B * N, 128, 0, stream>>>(xt, tp_w1, tp_b1, tp_w2, tp_b2, nt);
    guide_kernel<<<dim3(N / 16, N / 16, B), dim3(16, 16), 0, stream>>>(nt, gd);
    // vt aliases nt: stale f32 bytes reinterpreted as bf16 can be NaN in pad
    // tokens. Zero vt once per launch (layer GEMMs rewrite tokens 0..515 only).
    hipMemsetAsync(vt, 0, VT_BYTES, stream);
    build_tok_kernel<<<(B * T * L + 255) / 256, 256, 0, stream>>>(xt, x_mark, tokb);
    wconv_kernel<<<6240, 256, 0, stream>>>(wq, wk, wv, wo, w1, w2, emb_w, proj_w, wts);

    const int M = B * T;                   // 8256
    const int MT = (M + 127) / 128;        // 65
    mfma_gemm<<<dim3(D / 128, MT), 256, 0, stream>>>(tokb, wts + WT_EMB, emb_b, nullptr,
                                                     x, xb, M, D, L, 0, 0);
    for (int i = 0; i < 2; ++i) {
        const __hip_bfloat16* wqT = wts + WT_WQ + (size_t)i * D * D;
        const __hip_bfloat16* wkT = wts + WT_WK + (size_t)i * D * D;
        const __hip_bfloat16* wvT = wts + WT_WV + (size_t)i * D * D;
        const __hip_bfloat16* woT = wts + WT_WO + (size_t)i * D * D;
        mfma_gemm<<<dim3(D / 128, MT), 256, 0, stream>>>(xb, wqT, bq + i * D, nullptr,
                                                         nullptr, qbuf, M, D, D, 0, 0);
        mfma_gemm<<<dim3(D / 128, MT), 256, 0, stream>>>(xb, wkT, bk + i * D, nullptr,
                                                         nullptr, kbuf, M, D, D, 0, 0);
        mfma_gemm<<<dim3(D / 128, MT), 256, 0, stream>>>(xb, wvT, bv + i * D, nullptr,
                                                         nullptr, vt, M, D, D, 0, 1);
        attn_flash_kernel<<<B * H * 9, 256, 0, stream>>>(qbuf, kbuf, vt, gd, ctxb);
        mfma_gemm<<<dim3(D / 128, MT), 256, 0, stream>>>(ctxb, woT, bo + i * D, x,
                                                         x, nullptr, M, D, D, 0, 0);
        ln_kernel<<<M, 256, 0, stream>>>(x, ln1g + i * D, ln1b + i * D, x, xb);
        mfma_gemm<<<dim3(DFF / 128, MT), 256, 0, stream>>>(xb, wts + WT_W1 + (size_t)i * DFF * D,
                                                           b1 + i * DFF, nullptr,
                                                           nullptr, ffnb, M, DFF, D, 1, 0);
        mfma_gemm<<<dim3(D / 128, MT), 256, 0, stream>>>(ffnb, wts + WT_W2 + (size_t)i * DFF * D,
                                                         b2 + i * D, x, x, nullptr, M, D, DFF, 0, 0);
        ln_kernel<<<M, 256, 0, stream>>>(x, ln2g + i * D, ln2b + i * D, x, xb);
    }
    ln_kernel<<<M, 256, 0, stream>>>(x, normg, normb, x, xb);
    mfma_gemm<<<dim3(1, MT), 256, 0, stream>>>(xb, wts + WT_PROJ, proj_b, nullptr,
                                               dec, nullptr, M, PRED, D, 0, 0);
    revin_inv_kernel<<<(B * PRED * N + 255) / 256, 256, 0, stream>>>(dec, beta, gamma, mean, stdv,
                                                                     (float*)d_out);
}

// Round 6
// 917.237 us; speedup vs baseline: 8.9452x; 1.1467x over previous
//
#include <hip/hip_runtime.h>
#include <hip/hip_bf16.h>
#include <math.h>

#define B 16
#define L 96
#define N 512
#define D 512
#define H 8
#define E 64
#define DFF 2048
#define T 516
#define PRED 96
#define NMARK 4
#define VTS 576    // vt row stride (keys, padded from 516 to 9*64)
#define NCHUNK 9   // key chunks of 64

typedef __attribute__((ext_vector_type(8))) short bf16x8;
typedef __attribute__((ext_vector_type(4))) float f32x4;

// ---- workspace layout (BYTE offsets). Total 80,412,672 B ----
#define WS_MEAN 0              // f32 [B,N]
#define WS_STD  32768          // f32 [B,N]
#define WS_GD   65536          // bf16 [B,N,N] = 8,388,608 B
#define WS_X    8454144        // f32 [B,T,D] = 16,908,288 B (residual master)
#define WS_XB   25362432       // bf16 [B,T,D] (bf16 shadow; also ctxb)
#define WS_WTS  33816576       // bf16 transposed weights, 12,779,520 B
#define WS_QB   46596096       // bf16 [B,T,D]; also tokb(bf16), dec(f32), ffn base
#define WS_KB   55050240       // bf16 [B,T,D]; also xt(f32)
#define WS_VT   63504384       // bf16 [B,H,64,VTS] = 9,437,184 B; also nt(f32)
#define VT_BYTES 9437184
// ffnb = WS_QB .. WS_QB + 8256*2048*2 = 80,412,672 (spans qb,kb,vt; time-disjoint)

// weight-arena element offsets (bf16 elements from WS_WTS)
#define WT_WQ   0u
#define WT_WK   524288u
#define WT_WV   1048576u
#define WT_WO   1572864u
#define WT_W1   2097152u
#define WT_W2   4194304u
#define WT_EMB  6291456u
#define WT_PROJ 6340608u

// ---------- RevIN stats ----------
__global__ void revin_stats_kernel(const float* __restrict__ x, float* __restrict__ mean,
                                   float* __restrict__ stdv) {
    int i = blockIdx.x * blockDim.x + threadIdx.x;
    if (i >= B * N) return;
    int b = i >> 9;
    int n = i & (N - 1);
    const float* p = x + (size_t)b * L * N + n;
    float s = 0.f, ss = 0.f;
    for (int l = 0; l < L; ++l) {
        float v = p[(size_t)l * N];
        s += v; ss += v * v;
    }
    float m = s / (float)L;
    float var = ss / (float)L - m * m;
    mean[i] = m;
    stdv[i] = sqrtf(fmaxf(var, 0.f) + 1e-5f);
}

// ---------- normalize + transpose: xt[b,n,l] (f32) ----------
__global__ void norm_transpose_kernel(const float* __restrict__ x, const float* __restrict__ mean,
                                      const float* __restrict__ stdv, const float* __restrict__ gamma,
                                      const float* __restrict__ beta, float* __restrict__ xt) {
    int idx = blockIdx.x * blockDim.x + threadIdx.x;
    if (idx >= B * N * L) return;
    int l = idx % L;
    int n = (idx / L) % N;
    int b = idx / (L * N);
    float v = x[((size_t)b * L + l) * N + n];
    int bn = b * N + n;
    xt[idx] = (v - mean[bn]) / stdv[bn] * gamma[n] + beta[n];
}

// ---------- trend + normalized trend rows nt[b,n,l] (f32) ----------
__global__ void trend_nt_kernel(const float* __restrict__ xt, const float* __restrict__ tp_w1,
                                const float* __restrict__ tp_b1, const float* __restrict__ tp_w2,
                                const float* __restrict__ tp_b2, float* __restrict__ nt) {
    int bn = blockIdx.x;
    __shared__ float xr[96];
    __shared__ float P[97];
    __shared__ float wt[4];
    __shared__ float tr[96];
    __shared__ float nrm;
    int tid = threadIdx.x;
    if (tid < 96) xr[tid] = xt[(size_t)bn * 96 + tid];
    __syncthreads();
    if (tid == 0) {
        float s = 0.f, ss = 0.f;
        P[0] = 0.f;
        for (int l = 0; l < 96; ++l) { s += xr[l]; P[l + 1] = s; ss += xr[l] * xr[l]; }
        float m = s / 96.f;
        float var = ss / 96.f - m * m;
        float sd = sqrtf(fmaxf(var, 0.f) + 1e-6f);
        float h[16];
        for (int j = 0; j < 16; ++j) {
            float t = m * tp_w1[j] + sd * tp_w1[16 + j] + tp_b1[j];
            h[j] = fmaxf(t, 0.f);
        }
        float lg[4];
        for (int w = 0; w < 4; ++w) {
            float t = tp_b2[w];
            for (int j = 0; j < 16; ++j) t += h[j] * tp_w2[j * 4 + w];
            lg[w] = t;
        }
        float mx = fmaxf(fmaxf(lg[0], lg[1]), fmaxf(lg[2], lg[3]));
        float es = 0.f;
        for (int w = 0; w < 4; ++w) { lg[w] = expf(lg[w] - mx); es += lg[w]; }
        for (int w = 0; w < 4; ++w) wt[w] = lg[w] / es;
    }
    __syncthreads();
    const int WS[4] = {4, 8, 12, 24};
    if (tid < 96) {
        int l = tid;
        float t = 0.f;
        for (int wi = 0; wi < 4; ++wi) {
            int w = WS[wi];
            int lo = l - w + 1;
            float s;
            if (lo >= 0) s = P[l + 1] - P[lo];
            else         s = P[l + 1] - P[0] + (float)(-lo) * xr[0];
            t += (s / (float)w) * wt[wi];
        }
        tr[l] = t;
    }
    __syncthreads();
    if (tid == 0) {
        float s = 0.f;
        for (int l = 0; l < 96; ++l) s += tr[l] * tr[l];
        nrm = fmaxf(sqrtf(s), 1e-12f);
    }
    __syncthreads();
    if (tid < 96) nt[(size_t)bn * 96 + tid] = tr[tid] / nrm;
}

// ---------- guidance: sigmoid(nt @ nt^T) -> bf16 ----------
__global__ void guide_kernel(const float* __restrict__ nt, __hip_bfloat16* __restrict__ guide) {
    __shared__ float ri[16][97];
    __shared__ float rj[16][97];
    int b = blockIdx.z;
    int i0 = blockIdx.y * 16;
    int j0 = blockIdx.x * 16;
    int tx = threadIdx.x, ty = threadIdx.y;
    int tid = ty * 16 + tx;
    for (int t = tid; t < 16 * 96; t += 256) {
        int r = t / 96, c = t % 96;
        ri[r][c] = nt[((size_t)b * N + i0 + r) * 96 + c];
        rj[r][c] = nt[((size_t)b * N + j0 + r) * 96 + c];
    }
    __syncthreads();
    float acc = 0.f;
    for (int k = 0; k < 96; ++k) acc += ri[ty][k] * rj[tx][k];
    guide[((size_t)b * N + i0 + ty) * N + j0 + tx] =
        __float2bfloat16(1.f / (1.f + expf(-acc)));
}

// ---------- build tokens [B,T,L] bf16 ----------
__global__ void build_tok_kernel(const float* __restrict__ xt, const float* __restrict__ xmark,
                                 __hip_bfloat16* __restrict__ tok) {
    int idx = blockIdx.x * blockDim.x + threadIdx.x;
    if (idx >= B * T * L) return;
    int l = idx % L;
    int t = (idx / L) % T;
    int b = idx / (L * T);
    float v;
    if (t < N) v = xt[((size_t)b * N + t) * L + l];
    else       v = xmark[((size_t)b * L + l) * NMARK + (t - N)];
    tok[idx] = __float2bfloat16(v);
}

// ---------- weight transpose+convert: fp32 [K,N] -> bf16 [N,K] ----------
__global__ void wconv_kernel(const float* __restrict__ wq, const float* __restrict__ wk,
                             const float* __restrict__ wv, const float* __restrict__ wo,
                             const float* __restrict__ w1, const float* __restrict__ w2,
                             const float* __restrict__ emb, const float* __restrict__ proj,
                             __hip_bfloat16* __restrict__ wts) {
    int bid = blockIdx.x;
    const float* src; __hip_bfloat16* dst; int K, Nn, tloc;
    if (bid < 2048) {
        int seg = bid >> 9;
        int t = bid & 511;
        int layer = t >> 8;
        tloc = t & 255;
        K = 512; Nn = 512;
        const float* bases[4] = {wq, wk, wv, wo};
        src = bases[seg] + (size_t)layer * 512 * 512;
        dst = wts + (seg == 0 ? WT_WQ : seg == 1 ? WT_WK : seg == 2 ? WT_WV : WT_WO)
                  + (size_t)layer * 512 * 512;
    } else if (bid < 4096) {
        int t = bid - 2048;
        int layer = t >> 10;
        tloc = t & 1023;
        K = 512; Nn = 2048;
        src = w1 + (size_t)layer * 512 * 2048;
        dst = wts + WT_W1 + (size_t)layer * 2048 * 512;
    } else if (bid < 6144) {
        int t = bid - 4096;
        int layer = t >> 10;
        tloc = t & 1023;
        K = 2048; Nn = 512;
        src = w2 + (size_t)layer * 2048 * 512;
        dst = wts + WT_W2 + (size_t)layer * 512 * 2048;
    } else if (bid < 6192) {
        tloc = bid - 6144;
        K = 96; Nn = 512;
        src = emb; dst = wts + WT_EMB;
    } else {
        tloc = bid - 6192;
        K = 512; Nn = 96;
        src = proj; dst = wts + WT_PROJ;
    }
    int ntile = Nn >> 5;
    int tk = tloc / ntile, tn = tloc % ntile;
    int k0 = tk * 32, n0 = tn * 32;
    __shared__ float ld[32][33];
    int tid = threadIdx.x;
    for (int i = tid; i < 1024; i += 256) {
        int r = i >> 5, c = i & 31;
        ld[r][c] = src[(size_t)(k0 + r) * Nn + n0 + c];
    }
    __syncthreads();
    for (int i = tid; i < 1024; i += 256) {
        int r = i >> 5, c = i & 31;
        dst[(size_t)(n0 + r) * K + k0 + c] = __float2bfloat16(ld[c][r]);
    }
}

// ---------- MFMA bf16 GEMM: 128x128 tile, BK=32, 4 waves ----------
// Staging via global_load_lds width=16 (async direct-to-LDS; no VGPR round-trip).
__global__ __launch_bounds__(256, 2) void mfma_gemm(
    const __hip_bfloat16* __restrict__ A, const __hip_bfloat16* __restrict__ Wt,
    const float* __restrict__ bias, const float* __restrict__ res,
    float* __restrict__ outF, __hip_bfloat16* __restrict__ outB,
    int M, int Nn, int K, int act, int vtmode) {
    __shared__ __align__(16) __hip_bfloat16 As[128 * 32];
    __shared__ __align__(16) __hip_bfloat16 Bs[128 * 32];
    int tid = threadIdx.x;
    int lane = tid & 63;
    int wave = tid >> 6;
    int col = lane & 15;
    int quad = lane >> 4;
    int bm = blockIdx.y * 128;
    int bn = blockIdx.x * 128;
    int wm = (wave & 1) * 64;
    int wn = (wave >> 1) * 64;
    f32x4 acc[4][4];
    #pragma unroll
    for (int i = 0; i < 4; ++i)
        #pragma unroll
        for (int j = 0; j < 4; ++j) acc[i][j] = (f32x4){0.f, 0.f, 0.f, 0.f};

    for (int k0 = 0; k0 < K; k0 += 32) {
        // async stage: lane l of each wave writes LDS at wavebase + l*16B, which
        // matches As row-major [128][32] exactly (offset = c*16B, c = cbase+lane).
        #pragma unroll
        for (int cc = 0; cc < 2; ++cc) {
            int cbase = wave * 64 + cc * 256;
            int c = cbase + lane;
            int gm = bm + (c >> 2); if (gm >= M) gm = M - 1;
            const __hip_bfloat16* ga = A + (size_t)gm * K + k0 + (c & 3) * 8;
            __builtin_amdgcn_global_load_lds(
                (const __attribute__((address_space(1))) void*)ga,
                (__attribute__((address_space(3))) void*)(As + (size_t)cbase * 8), 16, 0, 0);
            int gn = bn + (c >> 2); if (gn >= Nn) gn = Nn - 1;
            const __hip_bfloat16* gb = Wt + (size_t)gn * K + k0 + (c & 3) * 8;
            __builtin_amdgcn_global_load_lds(
                (const __attribute__((address_space(1))) void*)gb,
                (__attribute__((address_space(3))) void*)(Bs + (size_t)cbase * 8), 16, 0, 0);
        }
        __syncthreads();
        bf16x8 af[4], bfr[4];
        #pragma unroll
        for (int i = 0; i < 4; ++i)
            af[i] = *(const bf16x8*)(const void*)&As[(wm + i * 16 + col) * 32 + quad * 8];
        #pragma unroll
        for (int j = 0; j < 4; ++j)
            bfr[j] = *(const bf16x8*)(const void*)&Bs[(wn + j * 16 + col) * 32 + quad * 8];
        #pragma unroll
        for (int i = 0; i < 4; ++i)
            #pragma unroll
            for (int j = 0; j < 4; ++j)
                acc[i][j] = __builtin_amdgcn_mfma_f32_16x16x32_bf16(af[i], bfr[j], acc[i][j], 0, 0, 0);
        __syncthreads();
    }
    #pragma unroll
    for (int i = 0; i < 4; ++i) {
        int gmb = bm + wm + i * 16 + quad * 4;
        #pragma unroll
        for (int j = 0; j < 4; ++j) {
            int gn = bn + wn + j * 16 + col;
            if (gn >= Nn) continue;
            float bs = bias[gn];
            #pragma unroll
            for (int r = 0; r < 4; ++r) {
                int gm = gmb + r;
                if (gm >= M) continue;
                float v = acc[i][j][r] + bs;
                if (act == 1) v = 0.5f * v * (1.f + erff(v * 0.70710678118654752f));
                if (res) v += res[(size_t)gm * Nn + gn];
                if (outF) outF[(size_t)gm * Nn + gn] = v;
                if (outB) {
                    if (vtmode) {
                        int bb = gm / T;
                        int tt = gm - bb * T;
                        outB[((size_t)bb * 512 + gn) * VTS + tt] = __float2bfloat16(v);
                    } else {
                        outB[(size_t)gm * Nn + gn] = __float2bfloat16(v);
                    }
                }
            }
        }
    }
}

// ---------- flash-style MFMA attention (guide gate staged in LDS) ----------
__global__ __launch_bounds__(256) void attn_flash_kernel(
    const __hip_bfloat16* __restrict__ qb, const __hip_bfloat16* __restrict__ kb,
    const __hip_bfloat16* __restrict__ vt, const __hip_bfloat16* __restrict__ gd,
    __hip_bfloat16* __restrict__ ctxb) {
    __shared__ __align__(16) __hip_bfloat16 Ks[64][72];    // keys x E
    __shared__ __align__(16) __hip_bfloat16 Vs[64][72];    // E x keys (V^T tile)
    __shared__ __align__(16) __hip_bfloat16 Pw[4][16][72]; // per-wave P tile
    __shared__ __align__(16) __hip_bfloat16 Gs[64][68];    // gate tile (stride 68: no quad conflicts)
    int bid = blockIdx.x;
    int sg = bid % 9;
    int h = (bid / 9) % H;
    int b = bid / (9 * H);
    int tid = threadIdx.x;
    int wave = tid >> 6, lane = tid & 63;
    int col = lane & 15, quad = lane >> 4;
    int q0b = sg * 64;
    int q0 = q0b + wave * 16;

    int qr = q0 + col; if (qr > T - 1) qr = T - 1;
    const __hip_bfloat16* qptr = qb + (size_t)(b * T + qr) * D + h * E + quad * 8;
    bf16x8 a0 = *(const bf16x8*)(const void*)qptr;
    bf16x8 a1 = *(const bf16x8*)(const void*)(qptr + 32);

    float m_r[4] = {-1e30f, -1e30f, -1e30f, -1e30f};
    float S[4] = {0.f, 0.f, 0.f, 0.f};
    float G[4] = {0.f, 0.f, 0.f, 0.f};
    f32x4 o[4];
    #pragma unroll
    for (int j = 0; j < 4; ++j) o[j] = (f32x4){0.f, 0.f, 0.f, 0.f};

    const __hip_bfloat16* vbase = vt + (size_t)((b * H + h) * E) * VTS;

    for (int kc = 0; kc < NCHUNK; ++kc) {
        __syncthreads();
        // cooperative stage: K chunk, V^T chunk, gate tile (all coalesced 16B)
        #pragma unroll
        for (int i = 0; i < 2; ++i) {
            int idx = tid + i * 256;        // 0..511
            int r = idx >> 3, s = idx & 7;
            int kr = kc * 64 + r; int krc = kr > T - 1 ? T - 1 : kr;
            *(bf16x8*)(void*)&Ks[r][s * 8] =
                *(const bf16x8*)(const void*)(kb + (size_t)(b * T + krc) * D + h * E + s * 8);
            *(bf16x8*)(void*)&Vs[r][s * 8] =
                *(const bf16x8*)(const void*)(vbase + (size_t)r * VTS + kc * 64 + s * 8);
            bf16x8 gval;
            int grow = q0b + r;
            if (grow < N && kc < 8) {   // keys kc*64..+63 all < N iff kc < 8
                gval = *(const bf16x8*)(const void*)(gd + ((size_t)b * N + grow) * N + kc * 64 + s * 8);
            } else {
                gval = (bf16x8){0x3F00, 0x3F00, 0x3F00, 0x3F00, 0x3F00, 0x3F00, 0x3F00, 0x3F00}; // bf16 0.5
            }
            *(bf16x8*)(void*)&Gs[r][s * 8] = gval;
        }
        __syncthreads();
        // QK^T
        f32x4 sc[4];
        #pragma unroll
        for (int sub = 0; sub < 4; ++sub) {
            bf16x8 b0 = *(const bf16x8*)(const void*)&Ks[sub * 16 + col][quad * 8];
            bf16x8 b1 = *(const bf16x8*)(const void*)&Ks[sub * 16 + col][32 + quad * 8];
            f32x4 acc = (f32x4){0.f, 0.f, 0.f, 0.f};
            acc = __builtin_amdgcn_mfma_f32_16x16x32_bf16(a0, b0, acc, 0, 0, 0);
            acc = __builtin_amdgcn_mfma_f32_16x16x32_bf16(a1, b1, acc, 0, 0, 0);
            sc[sub] = acc;
        }
        float cm[4] = {-1e30f, -1e30f, -1e30f, -1e30f};
        #pragma unroll
        for (int sub = 0; sub < 4; ++sub) {
            int key = kc * 64 + sub * 16 + col;
            #pragma unroll
            for (int r = 0; r < 4; ++r) {
                float v = sc[sub][r] * 0.125f;
                if (key >= T) v = -1e30f;
                sc[sub][r] = v;
                cm[r] = fmaxf(cm[r], v);
            }
        }
        #pragma unroll
        for (int r = 0; r < 4; ++r)
            #pragma unroll
            for (int d = 1; d < 16; d <<= 1) cm[r] = fmaxf(cm[r], __shfl_xor(cm[r], d, 64));
        float alpha[4];
        #pragma unroll
        for (int r = 0; r < 4; ++r) {
            float mn = fmaxf(m_r[r], cm[r]);
            alpha[r] = __expf(m_r[r] - mn);
            m_r[r] = mn;
            S[r] *= alpha[r];
            G[r] *= alpha[r];
        }
        #pragma unroll
        for (int j = 0; j < 4; ++j)
            #pragma unroll
            for (int r = 0; r < 4; ++r) o[j][r] *= alpha[r];
        #pragma unroll
        for (int sub = 0; sub < 4; ++sub) {
            #pragma unroll
            for (int r = 0; r < 4; ++r) {
                float p = __expf(sc[sub][r] - m_r[r]);   // masked -> exactly 0
                S[r] += p;
                float g = __bfloat162float(Gs[wave * 16 + quad * 4 + r][sub * 16 + col]);
                float t = p * g;
                G[r] += t;
                Pw[wave][quad * 4 + r][sub * 16 + col] = __float2bfloat16(t);
            }
        }
        #pragma unroll
        for (int ks = 0; ks < 2; ++ks) {
            bf16x8 pa = *(const bf16x8*)(const void*)&Pw[wave][col][ks * 32 + quad * 8];
            #pragma unroll
            for (int j = 0; j < 4; ++j) {
                bf16x8 bv = *(const bf16x8*)(const void*)&Vs[j * 16 + col][ks * 32 + quad * 8];
                o[j] = __builtin_amdgcn_mfma_f32_16x16x32_bf16(pa, bv, o[j], 0, 0, 0);
            }
        }
    }
    #pragma unroll
    for (int r = 0; r < 4; ++r) {
        #pragma unroll
        for (int d = 1; d < 16; d <<= 1) {
            S[r] += __shfl_xor(S[r], d, 64);
            G[r] += __shfl_xor(G[r], d, 64);
        }
    }
    float inv[4];
    #pragma unroll
    for (int r = 0; r < 4; ++r) inv[r] = 1.f / (G[r] + 1e-6f * S[r]);
    #pragma unroll
    for (int j = 0; j < 4; ++j)
        #pragma unroll
        for (int r = 0; r < 4; ++r) {
            int row = q0 + quad * 4 + r;
            if (row < T)
                ctxb[(size_t)(b * T + row) * D + h * E + j * 16 + col] =
                    __float2bfloat16(o[j][r] * inv[r]);
        }
}

// ---------- layernorm: wave-per-row, no barriers ----------
__global__ __launch_bounds__(256) void ln_kernel(const float* __restrict__ in, const float* __restrict__ g,
                          const float* __restrict__ bb, float* __restrict__ outF,
                          __hip_bfloat16* __restrict__ outB) {
    int row = blockIdx.x * 4 + (threadIdx.x >> 6);
    int lane = threadIdx.x & 63;
    const float* base = in + (size_t)row * D + lane * 8;
    float4 u0 = *(const float4*)base;
    float4 u1 = *(const float4*)(base + 4);
    float s = (u0.x + u0.y) + (u0.z + u0.w) + (u1.x + u1.y) + (u1.z + u1.w);
    float ss = u0.x * u0.x + u0.y * u0.y + u0.z * u0.z + u0.w * u0.w
             + u1.x * u1.x + u1.y * u1.y + u1.z * u1.z + u1.w * u1.w;
    #pragma unroll
    for (int d = 1; d < 64; d <<= 1) {
        s += __shfl_xor(s, d, 64);
        ss += __shfl_xor(ss, d, 64);
    }
    float m = s * (1.f / (float)D);
    float var = ss * (1.f / (float)D) - m * m;
    float rstd = rsqrtf(fmaxf(var, 0.f) + 1e-5f);
    float4 g0 = *(const float4*)(g + lane * 8);
    float4 g1 = *(const float4*)(g + lane * 8 + 4);
    float4 b0 = *(const float4*)(bb + lane * 8);
    float4 b1 = *(const float4*)(bb + lane * 8 + 4);
    float4 o0, o1;
    o0.x = (u0.x - m) * rstd * g0.x + b0.x;
    o0.y = (u0.y - m) * rstd * g0.y + b0.y;
    o0.z = (u0.z - m) * rstd * g0.z + b0.z;
    o0.w = (u0.w - m) * rstd * g0.w + b0.w;
    o1.x = (u1.x - m) * rstd * g1.x + b1.x;
    o1.y = (u1.y - m) * rstd * g1.y + b1.y;
    o1.z = (u1.z - m) * rstd * g1.z + b1.z;
    o1.w = (u1.w - m) * rstd * g1.w + b1.w;
    *(float4*)(outF + (size_t)row * D + lane * 8) = o0;
    *(float4*)(outF + (size_t)row * D + lane * 8 + 4) = o1;
    __align__(16) __hip_bfloat16 tmp[8];
    tmp[0] = __float2bfloat16(o0.x); tmp[1] = __float2bfloat16(o0.y);
    tmp[2] = __float2bfloat16(o0.z); tmp[3] = __float2bfloat16(o0.w);
    tmp[4] = __float2bfloat16(o1.x); tmp[5] = __float2bfloat16(o1.y);
    tmp[6] = __float2bfloat16(o1.z); tmp[7] = __float2bfloat16(o1.w);
    *(bf16x8*)(void*)(outB + (size_t)row * D + lane * 8) = *(const bf16x8*)(const void*)tmp;
}

// ---------- final: LDS-tiled transpose + RevIN inverse (coalesced both sides) ----------
__global__ __launch_bounds__(256) void revin_inv_kernel(
    const float* __restrict__ dec, const float* __restrict__ beta,
    const float* __restrict__ gamma, const float* __restrict__ mean,
    const float* __restrict__ stdv, float* __restrict__ out) {
    __shared__ float tile[64][33];
    int b = blockIdx.x;
    int n0 = blockIdx.y * 64;
    int p0 = blockIdx.z * 32;
    int t = threadIdx.x;
    int pl = t & 31, nb = t >> 5;          // load: 32 p-cols, 8 n-rows/pass
    #pragma unroll
    for (int i = 0; i < 8; ++i) {
        int nl = nb + i * 8;
        tile[nl][pl] = dec[((size_t)b * T + n0 + nl) * PRED + p0 + pl];
    }
    __syncthreads();
    int nl = t & 63, pb = t >> 6;          // store: 64 n-cols, 4 p-rows/pass
    int n = n0 + nl;
    int bn = b * N + n;
    float be = beta[n], ga = gamma[n], sd = stdv[bn], mn = mean[bn];
    float scale = sd / (ga + 1e-5f);
    #pragma unroll
    for (int i = 0; i < 8; ++i) {
        int p = p0 + pb + i * 4;
        out[((size_t)b * PRED + p) * N + n] = (tile[nl][pb + i * 4] - be) * scale + mn;
    }
}

extern "C" void kernel_launch(void* const* d_in, const int* in_sizes, int n_in,
                              void* d_out, int out_size, void* d_ws, size_t ws_size,
                              hipStream_t stream) {
    const float* x_enc  = (const float*)d_in[0];
    const float* x_mark = (const float*)d_in[1];
    const float* gamma  = (const float*)d_in[4];
    const float* beta   = (const float*)d_in[5];
    const float* tp_w1  = (const float*)d_in[6];
    const float* tp_b1  = (const float*)d_in[7];
    const float* tp_w2  = (const float*)d_in[8];
    const float* tp_b2  = (const float*)d_in[9];
    const float* emb_w  = (const float*)d_in[10];
    const float* emb_b  = (const float*)d_in[11];
    const float* wq = (const float*)d_in[12];
    const float* bq = (const float*)d_in[13];
    const float* wk = (const float*)d_in[14];
    const float* bk = (const float*)d_in[15];
    const float* wv = (const float*)d_in[16];
    const float* bv = (const float*)d_in[17];
    const float* wo = (const float*)d_in[18];
    const float* bo = (const float*)d_in[19];
    const float* w1 = (const float*)d_in[20];
    const float* b1 = (const float*)d_in[21];
    const float* w2 = (const float*)d_in[22];
    const float* b2 = (const float*)d_in[23];
    const float* ln1g = (const float*)d_in[24];
    const float* ln1b = (const float*)d_in[25];
    const float* ln2g = (const float*)d_in[26];
    const float* ln2b = (const float*)d_in[27];
    const float* normg = (const float*)d_in[28];
    const float* normb = (const float*)d_in[29];
    const float* proj_w = (const float*)d_in[30];
    const float* proj_b = (const float*)d_in[31];

    char* ws = (char*)d_ws;
    float* mean = (float*)(ws + WS_MEAN);
    float* stdv = (float*)(ws + WS_STD);
    __hip_bfloat16* gd  = (__hip_bfloat16*)(ws + WS_GD);
    float* x            = (float*)(ws + WS_X);
    __hip_bfloat16* xb  = (__hip_bfloat16*)(ws + WS_XB);
    __hip_bfloat16* wts = (__hip_bfloat16*)(ws + WS_WTS);
    __hip_bfloat16* qbuf = (__hip_bfloat16*)(ws + WS_QB);
    __hip_bfloat16* kbuf = (__hip_bfloat16*)(ws + WS_KB);
    __hip_bfloat16* vt   = (__hip_bfloat16*)(ws + WS_VT);
    float* xt  = (float*)(ws + WS_KB);
    float* nt  = (float*)(ws + WS_VT);
    __hip_bfloat16* tokb = (__hip_bfloat16*)(ws + WS_QB);
    __hip_bfloat16* ctxb = xb;
    __hip_bfloat16* ffnb = (__hip_bfloat16*)(ws + WS_QB);
    float* dec = (float*)(ws + WS_QB);

    revin_stats_kernel<<<(B * N + 255) / 256, 256, 0, stream>>>(x_enc, mean, stdv);
    norm_transpose_kernel<<<(B * N * L + 255) / 256, 256, 0, stream>>>(x_enc, mean, stdv, gamma, beta, xt);
    trend_nt_kernel<<<B * N, 128, 0, stream>>>(xt, tp_w1, tp_b1, tp_w2, tp_b2, nt);
    guide_kernel<<<dim3(N / 16, N / 16, B), dim3(16, 16), 0, stream>>>(nt, gd);
    // vt aliases nt: stale f32 bytes as bf16 can be NaN in pad tokens; 0*NaN=NaN
    // in the PV MFMA. Zero once per launch (layer GEMMs rewrite tokens 0..515).
    hipMemsetAsync(vt, 0, VT_BYTES, stream);
    build_tok_kernel<<<(B * T * L + 255) / 256, 256, 0, stream>>>(xt, x_mark, tokb);
    wconv_kernel<<<6240, 256, 0, stream>>>(wq, wk, wv, wo, w1, w2, emb_w, proj_w, wts);

    const int M = B * T;                   // 8256
    const int MT = (M + 127) / 128;        // 65
    mfma_gemm<<<dim3(D / 128, MT), 256, 0, stream>>>(tokb, wts + WT_EMB, emb_b, nullptr,
                                                     x, xb, M, D, L, 0, 0);
    for (int i = 0; i < 2; ++i) {
        const __hip_bfloat16* wqT = wts + WT_WQ + (size_t)i * D * D;
        const __hip_bfloat16* wkT = wts + WT_WK + (size_t)i * D * D;
        const __hip_bfloat16* wvT = wts + WT_WV + (size_t)i * D * D;
        const __hip_bfloat16* woT = wts + WT_WO + (size_t)i * D * D;
        mfma_gemm<<<dim3(D / 128, MT), 256, 0, stream>>>(xb, wqT, bq + i * D, nullptr,
                                                         nullptr, qbuf, M, D, D, 0, 0);
        mfma_gemm<<<dim3(D / 128, MT), 256, 0, stream>>>(xb, wkT, bk + i * D, nullptr,
                                                         nullptr, kbuf, M, D, D, 0, 0);
        mfma_gemm<<<dim3(D / 128, MT), 256, 0, stream>>>(xb, wvT, bv + i * D, nullptr,
                                                         nullptr, vt, M, D, D, 0, 1);
        attn_flash_kernel<<<B * H * 9, 256, 0, stream>>>(qbuf, kbuf, vt, gd, ctxb);
        mfma_gemm<<<dim3(D / 128, MT), 256, 0, stream>>>(ctxb, woT, bo + i * D, x,
                                                         x, nullptr, M, D, D, 0, 0);
        ln_kernel<<<M / 4, 256, 0, stream>>>(x, ln1g + i * D, ln1b + i * D, x, xb);
        mfma_gemm<<<dim3(DFF / 128, MT), 256, 0, stream>>>(xb, wts + WT_W1 + (size_t)i * DFF * D,
                                                           b1 + i * DFF, nullptr,
                                                           nullptr, ffnb, M, DFF, D, 1, 0);
        mfma_gemm<<<dim3(D / 128, MT), 256, 0, stream>>>(ffnb, wts + WT_W2 + (size_t)i * DFF * D,
                                                         b2 + i * D, x, x, nullptr, M, D, DFF, 0, 0);
        ln_kernel<<<M / 4, 256, 0, stream>>>(x, ln2g + i * D, ln2b + i * D, x, xb);
    }
    ln_kernel<<<M / 4, 256, 0, stream>>>(x, normg, normb, x, xb);
    mfma_gemm<<<dim3(1, MT), 256, 0, stream>>>(xb, wts + WT_PROJ, proj_b, nullptr,
                                               dec, nullptr, M, PRED, D, 0, 0);
    revin_inv_kernel<<<dim3(B, N / 64, PRED / 32), 256, 0, stream>>>(dec, beta, gamma, mean, stdv,
                                                                     (float*)d_out);
}

// Round 7
// 730.308 us; speedup vs baseline: 11.2348x; 1.2560x over previous
//
#include <hip/hip_runtime.h>
#include <hip/hip_bf16.h>
#include <math.h>

#define B 16
#define L 96
#define N 512
#define D 512
#define H 8
#define E 64
#define DFF 2048
#define T 516
#define PRED 96
#define NMARK 4
#define VTS 576    // vt row stride (keys, padded from 516 to 9*64)
#define NCHUNK 9   // key chunks of 64

typedef __attribute__((ext_vector_type(8))) short bf16x8;
typedef __attribute__((ext_vector_type(4))) float f32x4;

// ---- workspace layout (BYTE offsets). Total 80,412,672 B ----
#define WS_MEAN 0              // f32 [B,N]
#define WS_STD  32768          // f32 [B,N]
#define WS_GD   65536          // bf16 [B,N,N] = 8,388,608 B
#define WS_X    8454144        // f32 [B,T,D] = 16,908,288 B (residual master)
#define WS_XB   25362432       // bf16 [B,T,D] (bf16 shadow; also ctxb)
#define WS_WTS  33816576       // bf16 transposed weights, 12,779,520 B
#define WS_QB   46596096       // bf16 [B,T,D]; also tokb(bf16), dec(f32), ffn base
#define WS_KB   55050240       // bf16 [B,T,D]; also xt(f32)
#define WS_VT   63504384       // bf16 [B,H,64,VTS] = 9,437,184 B; also nt(f32)
#define VT_BYTES 9437184
// ffnb = WS_QB .. WS_QB + 8256*2048*2 = 80,412,672 (spans qb,kb,vt; time-disjoint)

// weight-arena element offsets (bf16 elements from WS_WTS)
#define WT_WQ   0u
#define WT_WK   524288u
#define WT_WV   1048576u
#define WT_WO   1572864u
#define WT_W1   2097152u
#define WT_W2   4194304u
#define WT_EMB  6291456u
#define WT_PROJ 6340608u

// ---------- RevIN stats ----------
__global__ void revin_stats_kernel(const float* __restrict__ x, float* __restrict__ mean,
                                   float* __restrict__ stdv) {
    int i = blockIdx.x * blockDim.x + threadIdx.x;
    if (i >= B * N) return;
    int b = i >> 9;
    int n = i & (N - 1);
    const float* p = x + (size_t)b * L * N + n;
    float s = 0.f, ss = 0.f;
    for (int l = 0; l < L; ++l) {
        float v = p[(size_t)l * N];
        s += v; ss += v * v;
    }
    float m = s / (float)L;
    float var = ss / (float)L - m * m;
    mean[i] = m;
    stdv[i] = sqrtf(fmaxf(var, 0.f) + 1e-5f);
}

// ---------- normalize + transpose: xt[b,n,l] (f32) ----------
__global__ void norm_transpose_kernel(const float* __restrict__ x, const float* __restrict__ mean,
                                      const float* __restrict__ stdv, const float* __restrict__ gamma,
                                      const float* __restrict__ beta, float* __restrict__ xt) {
    int idx = blockIdx.x * blockDim.x + threadIdx.x;
    if (idx >= B * N * L) return;
    int l = idx % L;
    int n = (idx / L) % N;
    int b = idx / (L * N);
    float v = x[((size_t)b * L + l) * N + n];
    int bn = b * N + n;
    xt[idx] = (v - mean[bn]) / stdv[bn] * gamma[n] + beta[n];
}

// ---------- trend + normalized trend rows nt[b,n,l] (f32) ----------
__global__ void trend_nt_kernel(const float* __restrict__ xt, const float* __restrict__ tp_w1,
                                const float* __restrict__ tp_b1, const float* __restrict__ tp_w2,
                                const float* __restrict__ tp_b2, float* __restrict__ nt) {
    int bn = blockIdx.x;
    __shared__ float xr[96];
    __shared__ float P[97];
    __shared__ float wt[4];
    __shared__ float tr[96];
    __shared__ float nrm;
    int tid = threadIdx.x;
    if (tid < 96) xr[tid] = xt[(size_t)bn * 96 + tid];
    __syncthreads();
    if (tid == 0) {
        float s = 0.f, ss = 0.f;
        P[0] = 0.f;
        for (int l = 0; l < 96; ++l) { s += xr[l]; P[l + 1] = s; ss += xr[l] * xr[l]; }
        float m = s / 96.f;
        float var = ss / 96.f - m * m;
        float sd = sqrtf(fmaxf(var, 0.f) + 1e-6f);
        float h[16];
        for (int j = 0; j < 16; ++j) {
            float t = m * tp_w1[j] + sd * tp_w1[16 + j] + tp_b1[j];
            h[j] = fmaxf(t, 0.f);
        }
        float lg[4];
        for (int w = 0; w < 4; ++w) {
            float t = tp_b2[w];
            for (int j = 0; j < 16; ++j) t += h[j] * tp_w2[j * 4 + w];
            lg[w] = t;
        }
        float mx = fmaxf(fmaxf(lg[0], lg[1]), fmaxf(lg[2], lg[3]));
        float es = 0.f;
        for (int w = 0; w < 4; ++w) { lg[w] = expf(lg[w] - mx); es += lg[w]; }
        for (int w = 0; w < 4; ++w) wt[w] = lg[w] / es;
    }
    __syncthreads();
    const int WS[4] = {4, 8, 12, 24};
    if (tid < 96) {
        int l = tid;
        float t = 0.f;
        for (int wi = 0; wi < 4; ++wi) {
            int w = WS[wi];
            int lo = l - w + 1;
            float s;
            if (lo >= 0) s = P[l + 1] - P[lo];
            else         s = P[l + 1] - P[0] + (float)(-lo) * xr[0];
            t += (s / (float)w) * wt[wi];
        }
        tr[l] = t;
    }
    __syncthreads();
    if (tid == 0) {
        float s = 0.f;
        for (int l = 0; l < 96; ++l) s += tr[l] * tr[l];
        nrm = fmaxf(sqrtf(s), 1e-12f);
    }
    __syncthreads();
    if (tid < 96) nt[(size_t)bn * 96 + tid] = tr[tid] / nrm;
}

// ---------- guidance: sigmoid(nt @ nt^T) -> bf16 ----------
__global__ void guide_kernel(const float* __restrict__ nt, __hip_bfloat16* __restrict__ guide) {
    __shared__ float ri[16][97];
    __shared__ float rj[16][97];
    int b = blockIdx.z;
    int i0 = blockIdx.y * 16;
    int j0 = blockIdx.x * 16;
    int tx = threadIdx.x, ty = threadIdx.y;
    int tid = ty * 16 + tx;
    for (int t = tid; t < 16 * 96; t += 256) {
        int r = t / 96, c = t % 96;
        ri[r][c] = nt[((size_t)b * N + i0 + r) * 96 + c];
        rj[r][c] = nt[((size_t)b * N + j0 + r) * 96 + c];
    }
    __syncthreads();
    float acc = 0.f;
    for (int k = 0; k < 96; ++k) acc += ri[ty][k] * rj[tx][k];
    guide[((size_t)b * N + i0 + ty) * N + j0 + tx] =
        __float2bfloat16(1.f / (1.f + expf(-acc)));
}

// ---------- build tokens [B,T,L] bf16 ----------
__global__ void build_tok_kernel(const float* __restrict__ xt, const float* __restrict__ xmark,
                                 __hip_bfloat16* __restrict__ tok) {
    int idx = blockIdx.x * blockDim.x + threadIdx.x;
    if (idx >= B * T * L) return;
    int l = idx % L;
    int t = (idx / L) % T;
    int b = idx / (L * T);
    float v;
    if (t < N) v = xt[((size_t)b * N + t) * L + l];
    else       v = xmark[((size_t)b * L + l) * NMARK + (t - N)];
    tok[idx] = __float2bfloat16(v);
}

// ---------- weight transpose+convert: fp32 [K,N] -> bf16 [N,K] ----------
__global__ void wconv_kernel(const float* __restrict__ wq, const float* __restrict__ wk,
                             const float* __restrict__ wv, const float* __restrict__ wo,
                             const float* __restrict__ w1, const float* __restrict__ w2,
                             const float* __restrict__ emb, const float* __restrict__ proj,
                             __hip_bfloat16* __restrict__ wts) {
    int bid = blockIdx.x;
    const float* src; __hip_bfloat16* dst; int K, Nn, tloc;
    if (bid < 2048) {
        int seg = bid >> 9;
        int t = bid & 511;
        int layer = t >> 8;
        tloc = t & 255;
        K = 512; Nn = 512;
        const float* bases[4] = {wq, wk, wv, wo};
        src = bases[seg] + (size_t)layer * 512 * 512;
        dst = wts + (seg == 0 ? WT_WQ : seg == 1 ? WT_WK : seg == 2 ? WT_WV : WT_WO)
                  + (size_t)layer * 512 * 512;
    } else if (bid < 4096) {
        int t = bid - 2048;
        int layer = t >> 10;
        tloc = t & 1023;
        K = 512; Nn = 2048;
        src = w1 + (size_t)layer * 512 * 2048;
        dst = wts + WT_W1 + (size_t)layer * 2048 * 512;
    } else if (bid < 6144) {
        int t = bid - 4096;
        int layer = t >> 10;
        tloc = t & 1023;
        K = 2048; Nn = 512;
        src = w2 + (size_t)layer * 2048 * 512;
        dst = wts + WT_W2 + (size_t)layer * 512 * 2048;
    } else if (bid < 6192) {
        tloc = bid - 6144;
        K = 96; Nn = 512;
        src = emb; dst = wts + WT_EMB;
    } else {
        tloc = bid - 6192;
        K = 512; Nn = 96;
        src = proj; dst = wts + WT_PROJ;
    }
    int ntile = Nn >> 5;
    int tk = tloc / ntile, tn = tloc % ntile;
    int k0 = tk * 32, n0 = tn * 32;
    __shared__ float ld[32][33];
    int tid = threadIdx.x;
    for (int i = tid; i < 1024; i += 256) {
        int r = i >> 5, c = i & 31;
        ld[r][c] = src[(size_t)(k0 + r) * Nn + n0 + c];
    }
    __syncthreads();
    for (int i = tid; i < 1024; i += 256) {
        int r = i >> 5, c = i & 31;
        dst[(size_t)(n0 + r) * K + k0 + c] = __float2bfloat16(ld[c][r]);
    }
}

// ---------- templated MFMA bf16 GEMM: TM x TN tile, BK=32, 4 waves ----------
// 1-D grid of 8*ceil(nbm/8)*nbn blocks, XCD-swizzled: xcd = id&7 owns a bm
// stripe (bm ≡ xcd mod 8), bn varies fastest -> same-A-row blocks co-locate on
// one XCD's L2. Staging via global_load_lds width=16.
template<int TM, int TN>
__global__ __launch_bounds__(256, 2) void mfma_gemm_t(
    const __hip_bfloat16* __restrict__ A, const __hip_bfloat16* __restrict__ Wt,
    const float* __restrict__ bias, const float* __restrict__ res,
    float* __restrict__ outF, __hip_bfloat16* __restrict__ outB,
    int M, int Nn, int K, int act, int vtmode, int nbm, int nbn) {
    constexpr int WM = TM / 2, WN = TN / 2;
    constexpr int FI = WM / 16, FJ = WN / 16;
    __shared__ __align__(16) __hip_bfloat16 As[TM * 32];
    __shared__ __align__(16) __hip_bfloat16 Bs[TN * 32];
    int id = blockIdx.x;
    int xcd = id & 7, slot = id >> 3;
    int bmb = xcd + 8 * (slot / nbn);
    int bnb = slot % nbn;
    if (bmb >= nbm) return;
    int bm = bmb * TM;
    int bn = bnb * TN;
    int tid = threadIdx.x;
    int lane = tid & 63;
    int wave = tid >> 6;
    int col = lane & 15;
    int quad = lane >> 4;
    int wm = (wave & 1) * WM;
    int wn = (wave >> 1) * WN;
    f32x4 acc[FI][FJ];
    #pragma unroll
    for (int i = 0; i < FI; ++i)
        #pragma unroll
        for (int j = 0; j < FJ; ++j) acc[i][j] = (f32x4){0.f, 0.f, 0.f, 0.f};

    for (int k0 = 0; k0 < K; k0 += 32) {
        #pragma unroll
        for (int cc = 0; cc < TM / 64; ++cc) {
            int cbase = cc * 256 + wave * 64;
            int c = cbase + lane;
            int gm = bm + (c >> 2); if (gm >= M) gm = M - 1;
            const __hip_bfloat16* ga = A + (size_t)gm * K + k0 + (c & 3) * 8;
            __builtin_amdgcn_global_load_lds(
                (const __attribute__((address_space(1))) void*)ga,
                (__attribute__((address_space(3))) void*)(As + (size_t)cbase * 8), 16, 0, 0);
        }
        #pragma unroll
        for (int cc = 0; cc < TN / 64; ++cc) {
            int cbase = cc * 256 + wave * 64;
            int c = cbase + lane;
            int gn = bn + (c >> 2); if (gn >= Nn) gn = Nn - 1;
            const __hip_bfloat16* gb = Wt + (size_t)gn * K + k0 + (c & 3) * 8;
            __builtin_amdgcn_global_load_lds(
                (const __attribute__((address_space(1))) void*)gb,
                (__attribute__((address_space(3))) void*)(Bs + (size_t)cbase * 8), 16, 0, 0);
        }
        __syncthreads();
        bf16x8 af[FI], bfr[FJ];
        #pragma unroll
        for (int i = 0; i < FI; ++i)
            af[i] = *(const bf16x8*)(const void*)&As[(wm + i * 16 + col) * 32 + quad * 8];
        #pragma unroll
        for (int j = 0; j < FJ; ++j)
            bfr[j] = *(const bf16x8*)(const void*)&Bs[(wn + j * 16 + col) * 32 + quad * 8];
        #pragma unroll
        for (int i = 0; i < FI; ++i)
            #pragma unroll
            for (int j = 0; j < FJ; ++j)
                acc[i][j] = __builtin_amdgcn_mfma_f32_16x16x32_bf16(af[i], bfr[j], acc[i][j], 0, 0, 0);
        __syncthreads();
    }
    #pragma unroll
    for (int i = 0; i < FI; ++i) {
        int gmb = bm + wm + i * 16 + quad * 4;
        #pragma unroll
        for (int j = 0; j < FJ; ++j) {
            int gn = bn + wn + j * 16 + col;
            if (gn >= Nn) continue;
            float bs = bias[gn];
            #pragma unroll
            for (int r = 0; r < 4; ++r) {
                int gm = gmb + r;
                if (gm >= M) continue;
                float v = acc[i][j][r] + bs;
                if (act == 1) v = 0.5f * v * (1.f + erff(v * 0.70710678118654752f));
                if (res) v += res[(size_t)gm * Nn + gn];
                if (outF) outF[(size_t)gm * Nn + gn] = v;
                if (outB) {
                    if (vtmode) {
                        int bb = gm / T;
                        int tt = gm - bb * T;
                        outB[((size_t)bb * 512 + gn) * VTS + tt] = __float2bfloat16(v);
                    } else {
                        outB[(size_t)gm * Nn + gn] = __float2bfloat16(v);
                    }
                }
            }
        }
    }
}

// ---------- flash-style MFMA attention (guide gate staged in LDS) ----------
__global__ __launch_bounds__(256) void attn_flash_kernel(
    const __hip_bfloat16* __restrict__ qb, const __hip_bfloat16* __restrict__ kb,
    const __hip_bfloat16* __restrict__ vt, const __hip_bfloat16* __restrict__ gd,
    __hip_bfloat16* __restrict__ ctxb) {
    __shared__ __align__(16) __hip_bfloat16 Ks[64][72];    // keys x E
    __shared__ __align__(16) __hip_bfloat16 Vs[64][72];    // E x keys (V^T tile)
    __shared__ __align__(16) __hip_bfloat16 Pw[4][16][72]; // per-wave P tile
    __shared__ __align__(16) __hip_bfloat16 Gs[64][68];    // gate tile
    int bid = blockIdx.x;
    int sg = bid % 9;
    int h = (bid / 9) % H;
    int b = bid / (9 * H);
    int tid = threadIdx.x;
    int wave = tid >> 6, lane = tid & 63;
    int col = lane & 15, quad = lane >> 4;
    int q0b = sg * 64;
    int q0 = q0b + wave * 16;

    int qr = q0 + col; if (qr > T - 1) qr = T - 1;
    const __hip_bfloat16* qptr = qb + (size_t)(b * T + qr) * D + h * E + quad * 8;
    bf16x8 a0 = *(const bf16x8*)(const void*)qptr;
    bf16x8 a1 = *(const bf16x8*)(const void*)(qptr + 32);

    float m_r[4] = {-1e30f, -1e30f, -1e30f, -1e30f};
    float S[4] = {0.f, 0.f, 0.f, 0.f};
    float G[4] = {0.f, 0.f, 0.f, 0.f};
    f32x4 o[4];
    #pragma unroll
    for (int j = 0; j < 4; ++j) o[j] = (f32x4){0.f, 0.f, 0.f, 0.f};

    const __hip_bfloat16* vbase = vt + (size_t)((b * H + h) * E) * VTS;

    for (int kc = 0; kc < NCHUNK; ++kc) {
        __syncthreads();
        #pragma unroll
        for (int i = 0; i < 2; ++i) {
            int idx = tid + i * 256;
            int r = idx >> 3, s = idx & 7;
            int kr = kc * 64 + r; int krc = kr > T - 1 ? T - 1 : kr;
            *(bf16x8*)(void*)&Ks[r][s * 8] =
                *(const bf16x8*)(const void*)(kb + (size_t)(b * T + krc) * D + h * E + s * 8);
            *(bf16x8*)(void*)&Vs[r][s * 8] =
                *(const bf16x8*)(const void*)(vbase + (size_t)r * VTS + kc * 64 + s * 8);
            bf16x8 gval;
            int grow = q0b + r;
            if (grow < N && kc < 8) {
                gval = *(const bf16x8*)(const void*)(gd + ((size_t)b * N + grow) * N + kc * 64 + s * 8);
            } else {
                gval = (bf16x8){0x3F00, 0x3F00, 0x3F00, 0x3F00, 0x3F00, 0x3F00, 0x3F00, 0x3F00};
            }
            *(bf16x8*)(void*)&Gs[r][s * 8] = gval;
        }
        __syncthreads();
        f32x4 sc[4];
        #pragma unroll
        for (int sub = 0; sub < 4; ++sub) {
            bf16x8 b0 = *(const bf16x8*)(const void*)&Ks[sub * 16 + col][quad * 8];
            bf16x8 b1 = *(const bf16x8*)(const void*)&Ks[sub * 16 + col][32 + quad * 8];
            f32x4 acc = (f32x4){0.f, 0.f, 0.f, 0.f};
            acc = __builtin_amdgcn_mfma_f32_16x16x32_bf16(a0, b0, acc, 0, 0, 0);
            acc = __builtin_amdgcn_mfma_f32_16x16x32_bf16(a1, b1, acc, 0, 0, 0);
            sc[sub] = acc;
        }
        float cm[4] = {-1e30f, -1e30f, -1e30f, -1e30f};
        #pragma unroll
        for (int sub = 0; sub < 4; ++sub) {
            int key = kc * 64 + sub * 16 + col;
            #pragma unroll
            for (int r = 0; r < 4; ++r) {
                float v = sc[sub][r] * 0.125f;
                if (key >= T) v = -1e30f;
                sc[sub][r] = v;
                cm[r] = fmaxf(cm[r], v);
            }
        }
        #pragma unroll
        for (int r = 0; r < 4; ++r)
            #pragma unroll
            for (int d = 1; d < 16; d <<= 1) cm[r] = fmaxf(cm[r], __shfl_xor(cm[r], d, 64));
        float alpha[4];
        #pragma unroll
        for (int r = 0; r < 4; ++r) {
            float mn = fmaxf(m_r[r], cm[r]);
            alpha[r] = __expf(m_r[r] - mn);
            m_r[r] = mn;
            S[r] *= alpha[r];
            G[r] *= alpha[r];
        }
        #pragma unroll
        for (int j = 0; j < 4; ++j)
            #pragma unroll
            for (int r = 0; r < 4; ++r) o[j][r] *= alpha[r];
        #pragma unroll
        for (int sub = 0; sub < 4; ++sub) {
            #pragma unroll
            for (int r = 0; r < 4; ++r) {
                float p = __expf(sc[sub][r] - m_r[r]);
                S[r] += p;
                float g = __bfloat162float(Gs[wave * 16 + quad * 4 + r][sub * 16 + col]);
                float t = p * g;
                G[r] += t;
                Pw[wave][quad * 4 + r][sub * 16 + col] = __float2bfloat16(t);
            }
        }
        #pragma unroll
        for (int ks = 0; ks < 2; ++ks) {
            bf16x8 pa = *(const bf16x8*)(const void*)&Pw[wave][col][ks * 32 + quad * 8];
            #pragma unroll
            for (int j = 0; j < 4; ++j) {
                bf16x8 bv = *(const bf16x8*)(const void*)&Vs[j * 16 + col][ks * 32 + quad * 8];
                o[j] = __builtin_amdgcn_mfma_f32_16x16x32_bf16(pa, bv, o[j], 0, 0, 0);
            }
        }
    }
    #pragma unroll
    for (int r = 0; r < 4; ++r) {
        #pragma unroll
        for (int d = 1; d < 16; d <<= 1) {
            S[r] += __shfl_xor(S[r], d, 64);
            G[r] += __shfl_xor(G[r], d, 64);
        }
    }
    float inv[4];
    #pragma unroll
    for (int r = 0; r < 4; ++r) inv[r] = 1.f / (G[r] + 1e-6f * S[r]);
    #pragma unroll
    for (int j = 0; j < 4; ++j)
        #pragma unroll
        for (int r = 0; r < 4; ++r) {
            int row = q0 + quad * 4 + r;
            if (row < T)
                ctxb[(size_t)(b * T + row) * D + h * E + j * 16 + col] =
                    __float2bfloat16(o[j][r] * inv[r]);
        }
}

// ---------- layernorm: wave-per-row, no barriers ----------
__global__ __launch_bounds__(256) void ln_kernel(const float* __restrict__ in, const float* __restrict__ g,
                          const float* __restrict__ bb, float* __restrict__ outF,
                          __hip_bfloat16* __restrict__ outB) {
    int row = blockIdx.x * 4 + (threadIdx.x >> 6);
    int lane = threadIdx.x & 63;
    const float* base = in + (size_t)row * D + lane * 8;
    float4 u0 = *(const float4*)base;
    float4 u1 = *(const float4*)(base + 4);
    float s = (u0.x + u0.y) + (u0.z + u0.w) + (u1.x + u1.y) + (u1.z + u1.w);
    float ss = u0.x * u0.x + u0.y * u0.y + u0.z * u0.z + u0.w * u0.w
             + u1.x * u1.x + u1.y * u1.y + u1.z * u1.z + u1.w * u1.w;
    #pragma unroll
    for (int d = 1; d < 64; d <<= 1) {
        s += __shfl_xor(s, d, 64);
        ss += __shfl_xor(ss, d, 64);
    }
    float m = s * (1.f / (float)D);
    float var = ss * (1.f / (float)D) - m * m;
    float rstd = rsqrtf(fmaxf(var, 0.f) + 1e-5f);
    float4 g0 = *(const float4*)(g + lane * 8);
    float4 g1 = *(const float4*)(g + lane * 8 + 4);
    float4 b0 = *(const float4*)(bb + lane * 8);
    float4 b1 = *(const float4*)(bb + lane * 8 + 4);
    float4 o0, o1;
    o0.x = (u0.x - m) * rstd * g0.x + b0.x;
    o0.y = (u0.y - m) * rstd * g0.y + b0.y;
    o0.z = (u0.z - m) * rstd * g0.z + b0.z;
    o0.w = (u0.w - m) * rstd * g0.w + b0.w;
    o1.x = (u1.x - m) * rstd * g1.x + b1.x;
    o1.y = (u1.y - m) * rstd * g1.y + b1.y;
    o1.z = (u1.z - m) * rstd * g1.z + b1.z;
    o1.w = (u1.w - m) * rstd * g1.w + b1.w;
    *(float4*)(outF + (size_t)row * D + lane * 8) = o0;
    *(float4*)(outF + (size_t)row * D + lane * 8 + 4) = o1;
    __align__(16) __hip_bfloat16 tmp[8];
    tmp[0] = __float2bfloat16(o0.x); tmp[1] = __float2bfloat16(o0.y);
    tmp[2] = __float2bfloat16(o0.z); tmp[3] = __float2bfloat16(o0.w);
    tmp[4] = __float2bfloat16(o1.x); tmp[5] = __float2bfloat16(o1.y);
    tmp[6] = __float2bfloat16(o1.z); tmp[7] = __float2bfloat16(o1.w);
    *(bf16x8*)(void*)(outB + (size_t)row * D + lane * 8) = *(const bf16x8*)(const void*)tmp;
}

// ---------- final: LDS-tiled transpose + RevIN inverse ----------
__global__ __launch_bounds__(256) void revin_inv_kernel(
    const float* __restrict__ dec, const float* __restrict__ beta,
    const float* __restrict__ gamma, const float* __restrict__ mean,
    const float* __restrict__ stdv, float* __restrict__ out) {
    __shared__ float tile[64][33];
    int b = blockIdx.x;
    int n0 = blockIdx.y * 64;
    int p0 = blockIdx.z * 32;
    int t = threadIdx.x;
    int pl = t & 31, nb = t >> 5;
    #pragma unroll
    for (int i = 0; i < 8; ++i) {
        int nl = nb + i * 8;
        tile[nl][pl] = dec[((size_t)b * T + n0 + nl) * PRED + p0 + pl];
    }
    __syncthreads();
    int nl = t & 63, pb = t >> 6;
    int n = n0 + nl;
    int bn = b * N + n;
    float be = beta[n], ga = gamma[n], sd = stdv[bn], mn = mean[bn];
    float scale = sd / (ga + 1e-5f);
    #pragma unroll
    for (int i = 0; i < 8; ++i) {
        int p = p0 + pb + i * 4;
        out[((size_t)b * PRED + p) * N + n] = (tile[nl][pb + i * 4] - be) * scale + mn;
    }
}

static inline int swz_grid(int nbm, int nbn) { return 8 * ((nbm + 7) / 8) * nbn; }

extern "C" void kernel_launch(void* const* d_in, const int* in_sizes, int n_in,
                              void* d_out, int out_size, void* d_ws, size_t ws_size,
                              hipStream_t stream) {
    const float* x_enc  = (const float*)d_in[0];
    const float* x_mark = (const float*)d_in[1];
    const float* gamma  = (const float*)d_in[4];
    const float* beta   = (const float*)d_in[5];
    const float* tp_w1  = (const float*)d_in[6];
    const float* tp_b1  = (const float*)d_in[7];
    const float* tp_w2  = (const float*)d_in[8];
    const float* tp_b2  = (const float*)d_in[9];
    const float* emb_w  = (const float*)d_in[10];
    const float* emb_b  = (const float*)d_in[11];
    const float* wq = (const float*)d_in[12];
    const float* bq = (const float*)d_in[13];
    const float* wk = (const float*)d_in[14];
    const float* bk = (const float*)d_in[15];
    const float* wv = (const float*)d_in[16];
    const float* bv = (const float*)d_in[17];
    const float* wo = (const float*)d_in[18];
    const float* bo = (const float*)d_in[19];
    const float* w1 = (const float*)d_in[20];
    const float* b1 = (const float*)d_in[21];
    const float* w2 = (const float*)d_in[22];
    const float* b2 = (const float*)d_in[23];
    const float* ln1g = (const float*)d_in[24];
    const float* ln1b = (const float*)d_in[25];
    const float* ln2g = (const float*)d_in[26];
    const float* ln2b = (const float*)d_in[27];
    const float* normg = (const float*)d_in[28];
    const float* normb = (const float*)d_in[29];
    const float* proj_w = (const float*)d_in[30];
    const float* proj_b = (const float*)d_in[31];

    char* ws = (char*)d_ws;
    float* mean = (float*)(ws + WS_MEAN);
    float* stdv = (float*)(ws + WS_STD);
    __hip_bfloat16* gd  = (__hip_bfloat16*)(ws + WS_GD);
    float* x            = (float*)(ws + WS_X);
    __hip_bfloat16* xb  = (__hip_bfloat16*)(ws + WS_XB);
    __hip_bfloat16* wts = (__hip_bfloat16*)(ws + WS_WTS);
    __hip_bfloat16* qbuf = (__hip_bfloat16*)(ws + WS_QB);
    __hip_bfloat16* kbuf = (__hip_bfloat16*)(ws + WS_KB);
    __hip_bfloat16* vt   = (__hip_bfloat16*)(ws + WS_VT);
    float* xt  = (float*)(ws + WS_KB);
    float* nt  = (float*)(ws + WS_VT);
    __hip_bfloat16* tokb = (__hip_bfloat16*)(ws + WS_QB);
    __hip_bfloat16* ctxb = xb;
    __hip_bfloat16* ffnb = (__hip_bfloat16*)(ws + WS_QB);
    float* dec = (float*)(ws + WS_QB);

    revin_stats_kernel<<<(B * N + 255) / 256, 256, 0, stream>>>(x_enc, mean, stdv);
    norm_transpose_kernel<<<(B * N * L + 255) / 256, 256, 0, stream>>>(x_enc, mean, stdv, gamma, beta, xt);
    trend_nt_kernel<<<B * N, 128, 0, stream>>>(xt, tp_w1, tp_b1, tp_w2, tp_b2, nt);
    guide_kernel<<<dim3(N / 16, N / 16, B), dim3(16, 16), 0, stream>>>(nt, gd);
    // vt aliases nt: stale f32 bytes as bf16 can be NaN in pad tokens; 0*NaN=NaN
    // in the PV MFMA. Zero once per launch (layer GEMMs rewrite tokens 0..515).
    hipMemsetAsync(vt, 0, VT_BYTES, stream);
    build_tok_kernel<<<(B * T * L + 255) / 256, 256, 0, stream>>>(xt, x_mark, tokb);
    wconv_kernel<<<6240, 256, 0, stream>>>(wq, wk, wv, wo, w1, w2, emb_w, proj_w, wts);

    const int M = B * T;                   // 8256
    const int NBM64 = (M + 63) / 64;       // 129
    const int NBM128 = (M + 127) / 128;    // 65
    // emb: 64x64 tiles, nbn=8
    mfma_gemm_t<64, 64><<<swz_grid(NBM64, 8), 256, 0, stream>>>(
        tokb, wts + WT_EMB, emb_b, nullptr, x, xb, M, D, L, 0, 0, NBM64, 8);
    for (int i = 0; i < 2; ++i) {
        const __hip_bfloat16* wqT = wts + WT_WQ + (size_t)i * D * D;
        const __hip_bfloat16* wkT = wts + WT_WK + (size_t)i * D * D;
        const __hip_bfloat16* wvT = wts + WT_WV + (size_t)i * D * D;
        const __hip_bfloat16* woT = wts + WT_WO + (size_t)i * D * D;
        mfma_gemm_t<64, 64><<<swz_grid(NBM64, 8), 256, 0, stream>>>(
            xb, wqT, bq + i * D, nullptr, nullptr, qbuf, M, D, D, 0, 0, NBM64, 8);
        mfma_gemm_t<64, 64><<<swz_grid(NBM64, 8), 256, 0, stream>>>(
            xb, wkT, bk + i * D, nullptr, nullptr, kbuf, M, D, D, 0, 0, NBM64, 8);
        mfma_gemm_t<64, 64><<<swz_grid(NBM64, 8), 256, 0, stream>>>(
            xb, wvT, bv + i * D, nullptr, nullptr, vt, M, D, D, 0, 1, NBM64, 8);
        attn_flash_kernel<<<B * H * 9, 256, 0, stream>>>(qbuf, kbuf, vt, gd, ctxb);
        mfma_gemm_t<64, 64><<<swz_grid(NBM64, 8), 256, 0, stream>>>(
            ctxb, woT, bo + i * D, x, x, nullptr, M, D, D, 0, 0, NBM64, 8);
        ln_kernel<<<M / 4, 256, 0, stream>>>(x, ln1g + i * D, ln1b + i * D, x, xb);
        mfma_gemm_t<128, 128><<<swz_grid(NBM128, 16), 256, 0, stream>>>(
            xb, wts + WT_W1 + (size_t)i * DFF * D, b1 + i * DFF, nullptr,
            nullptr, ffnb, M, DFF, D, 1, 0, NBM128, 16);
        mfma_gemm_t<64, 64><<<swz_grid(NBM64, 8), 256, 0, stream>>>(
            ffnb, wts + WT_W2 + (size_t)i * DFF * D, b2 + i * D, x, x, nullptr,
            M, D, DFF, 0, 0, NBM64, 8);
        ln_kernel<<<M / 4, 256, 0, stream>>>(x, ln2g + i * D, ln2b + i * D, x, xb);
    }
    ln_kernel<<<M / 4, 256, 0, stream>>>(x, normg, normb, x, xb);
    mfma_gemm_t<64, 64><<<swz_grid(NBM64, 2), 256, 0, stream>>>(
        xb, wts + WT_PROJ, proj_b, nullptr, dec, nullptr, M, PRED, D, 0, 0, NBM64, 2);
    revin_inv_kernel<<<dim3(B, N / 64, PRED / 32), 256, 0, stream>>>(dec, beta, gamma, mean, stdv,
                                                                     (float*)d_out);
}

// Round 8
// 722.870 us; speedup vs baseline: 11.3505x; 1.0103x over previous
//
#include <hip/hip_runtime.h>
#include <hip/hip_bf16.h>
#include <math.h>

#define B 16
#define L 96
#define N 512
#define D 512
#define H 8
#define E 64
#define DFF 2048
#define T 516
#define PRED 96
#define NMARK 4
#define VTS 576    // vt row stride (keys, padded from 516 to 9*64)
#define NCHUNK 9   // key chunks of 64

typedef __attribute__((ext_vector_type(8))) short bf16x8;
typedef __attribute__((ext_vector_type(4))) float f32x4;

// ---- workspace layout (BYTE offsets). Total 80,412,672 B ----
#define WS_MEAN 0              // f32 [B,N]
#define WS_STD  32768          // f32 [B,N]
#define WS_GD   65536          // bf16 [B,N,N] = 8,388,608 B
#define WS_X    8454144        // f32 [B,T,D] = 16,908,288 B (residual master)
#define WS_XB   25362432       // bf16 [B,T,D] (bf16 shadow; also ctxb)
#define WS_WTS  33816576       // bf16 transposed weights, 12,779,520 B
#define WS_QB   46596096       // bf16 [B,T,D]; also tokb(bf16), dec(f32), ffn base
#define WS_KB   55050240       // bf16 [B,T,D]; also xt(f32)
#define WS_VT   63504384       // bf16 [B,H,64,VTS] = 9,437,184 B; also nt(f32)
#define VT_BYTES 9437184
// ffnb = WS_QB .. WS_QB + 8256*2048*2 = 80,412,672 (spans qb,kb,vt; time-disjoint)

// weight-arena element offsets (bf16 elements from WS_WTS)
#define WT_QKV  0u          // [2][1536][512]: rows 0..511 Q, 512..1023 K, 1024..1535 V
#define WT_WO   1572864u    // [2][512][512]
#define WT_W1   2097152u    // [2][2048][512]
#define WT_W2   4194304u    // [2][512][2048]
#define WT_EMB  6291456u    // [512][96]
#define WT_PROJ 6340608u    // [96][512]

// ---------- RevIN stats ----------
__global__ void revin_stats_kernel(const float* __restrict__ x, float* __restrict__ mean,
                                   float* __restrict__ stdv) {
    int i = blockIdx.x * blockDim.x + threadIdx.x;
    if (i >= B * N) return;
    int b = i >> 9;
    int n = i & (N - 1);
    const float* p = x + (size_t)b * L * N + n;
    float s = 0.f, ss = 0.f;
    for (int l = 0; l < L; ++l) {
        float v = p[(size_t)l * N];
        s += v; ss += v * v;
    }
    float m = s / (float)L;
    float var = ss / (float)L - m * m;
    mean[i] = m;
    stdv[i] = sqrtf(fmaxf(var, 0.f) + 1e-5f);
}

// ---------- normalize + transpose: xt[b,n,l] (f32) ----------
__global__ void norm_transpose_kernel(const float* __restrict__ x, const float* __restrict__ mean,
                                      const float* __restrict__ stdv, const float* __restrict__ gamma,
                                      const float* __restrict__ beta, float* __restrict__ xt) {
    int idx = blockIdx.x * blockDim.x + threadIdx.x;
    if (idx >= B * N * L) return;
    int l = idx % L;
    int n = (idx / L) % N;
    int b = idx / (L * N);
    float v = x[((size_t)b * L + l) * N + n];
    int bn = b * N + n;
    xt[idx] = (v - mean[bn]) / stdv[bn] * gamma[n] + beta[n];
}

// ---------- trend + normalized trend rows nt[b,n,l] (f32) ----------
__global__ void trend_nt_kernel(const float* __restrict__ xt, const float* __restrict__ tp_w1,
                                const float* __restrict__ tp_b1, const float* __restrict__ tp_w2,
                                const float* __restrict__ tp_b2, float* __restrict__ nt) {
    int bn = blockIdx.x;
    __shared__ float xr[96];
    __shared__ float P[97];
    __shared__ float wt[4];
    __shared__ float tr[96];
    __shared__ float nrm;
    int tid = threadIdx.x;
    if (tid < 96) xr[tid] = xt[(size_t)bn * 96 + tid];
    __syncthreads();
    if (tid == 0) {
        float s = 0.f, ss = 0.f;
        P[0] = 0.f;
        for (int l = 0; l < 96; ++l) { s += xr[l]; P[l + 1] = s; ss += xr[l] * xr[l]; }
        float m = s / 96.f;
        float var = ss / 96.f - m * m;
        float sd = sqrtf(fmaxf(var, 0.f) + 1e-6f);
        float h[16];
        for (int j = 0; j < 16; ++j) {
            float t = m * tp_w1[j] + sd * tp_w1[16 + j] + tp_b1[j];
            h[j] = fmaxf(t, 0.f);
        }
        float lg[4];
        for (int w = 0; w < 4; ++w) {
            float t = tp_b2[w];
            for (int j = 0; j < 16; ++j) t += h[j] * tp_w2[j * 4 + w];
            lg[w] = t;
        }
        float mx = fmaxf(fmaxf(lg[0], lg[1]), fmaxf(lg[2], lg[3]));
        float es = 0.f;
        for (int w = 0; w < 4; ++w) { lg[w] = expf(lg[w] - mx); es += lg[w]; }
        for (int w = 0; w < 4; ++w) wt[w] = lg[w] / es;
    }
    __syncthreads();
    const int WS[4] = {4, 8, 12, 24};
    if (tid < 96) {
        int l = tid;
        float t = 0.f;
        for (int wi = 0; wi < 4; ++wi) {
            int w = WS[wi];
            int lo = l - w + 1;
            float s;
            if (lo >= 0) s = P[l + 1] - P[lo];
            else         s = P[l + 1] - P[0] + (float)(-lo) * xr[0];
            t += (s / (float)w) * wt[wi];
        }
        tr[l] = t;
    }
    __syncthreads();
    if (tid == 0) {
        float s = 0.f;
        for (int l = 0; l < 96; ++l) s += tr[l] * tr[l];
        nrm = fmaxf(sqrtf(s), 1e-12f);
    }
    __syncthreads();
    if (tid < 96) nt[(size_t)bn * 96 + tid] = tr[tid] / nrm;
}

// ---------- guidance: sigmoid(nt @ nt^T) -> bf16 ----------
__global__ void guide_kernel(const float* __restrict__ nt, __hip_bfloat16* __restrict__ guide) {
    __shared__ float ri[16][97];
    __shared__ float rj[16][97];
    int b = blockIdx.z;
    int i0 = blockIdx.y * 16;
    int j0 = blockIdx.x * 16;
    int tx = threadIdx.x, ty = threadIdx.y;
    int tid = ty * 16 + tx;
    for (int t = tid; t < 16 * 96; t += 256) {
        int r = t / 96, c = t % 96;
        ri[r][c] = nt[((size_t)b * N + i0 + r) * 96 + c];
        rj[r][c] = nt[((size_t)b * N + j0 + r) * 96 + c];
    }
    __syncthreads();
    float acc = 0.f;
    for (int k = 0; k < 96; ++k) acc += ri[ty][k] * rj[tx][k];
    guide[((size_t)b * N + i0 + ty) * N + j0 + tx] =
        __float2bfloat16(1.f / (1.f + expf(-acc)));
}

// ---------- build tokens [B,T,L] bf16 ----------
__global__ void build_tok_kernel(const float* __restrict__ xt, const float* __restrict__ xmark,
                                 __hip_bfloat16* __restrict__ tok) {
    int idx = blockIdx.x * blockDim.x + threadIdx.x;
    if (idx >= B * T * L) return;
    int l = idx % L;
    int t = (idx / L) % T;
    int b = idx / (L * T);
    float v;
    if (t < N) v = xt[((size_t)b * N + t) * L + l];
    else       v = xmark[((size_t)b * L + l) * NMARK + (t - N)];
    tok[idx] = __float2bfloat16(v);
}

// ---------- weight transpose+convert: fp32 [K,N] -> bf16 [N,K] ----------
__global__ void wconv_kernel(const float* __restrict__ wq, const float* __restrict__ wk,
                             const float* __restrict__ wv, const float* __restrict__ wo,
                             const float* __restrict__ w1, const float* __restrict__ w2,
                             const float* __restrict__ emb, const float* __restrict__ proj,
                             __hip_bfloat16* __restrict__ wts) {
    int bid = blockIdx.x;
    const float* src; __hip_bfloat16* dst; int K, Nn, tloc;
    if (bid < 2048) {
        int seg = bid >> 9;          // 0=wq 1=wk 2=wv 3=wo
        int t = bid & 511;
        int layer = t >> 8;
        tloc = t & 255;
        K = 512; Nn = 512;
        const float* bases[4] = {wq, wk, wv, wo};
        src = bases[seg] + (size_t)layer * 512 * 512;
        if (seg < 3)   // fused QKV arena: [layer][seg*512 + n][k]
            dst = wts + WT_QKV + (size_t)layer * 1536 * 512 + (size_t)seg * 512 * 512;
        else
            dst = wts + WT_WO + (size_t)layer * 512 * 512;
    } else if (bid < 4096) {
        int t = bid - 2048;
        int layer = t >> 10;
        tloc = t & 1023;
        K = 512; Nn = 2048;
        src = w1 + (size_t)layer * 512 * 2048;
        dst = wts + WT_W1 + (size_t)layer * 2048 * 512;
    } else if (bid < 6144) {
        int t = bid - 4096;
        int layer = t >> 10;
        tloc = t & 1023;
        K = 2048; Nn = 512;
        src = w2 + (size_t)layer * 2048 * 512;
        dst = wts + WT_W2 + (size_t)layer * 512 * 2048;
    } else if (bid < 6192) {
        tloc = bid - 6144;
        K = 96; Nn = 512;
        src = emb; dst = wts + WT_EMB;
    } else {
        tloc = bid - 6192;
        K = 512; Nn = 96;
        src = proj; dst = wts + WT_PROJ;
    }
    int ntile = Nn >> 5;
    int tk = tloc / ntile, tn = tloc % ntile;
    int k0 = tk * 32, n0 = tn * 32;
    __shared__ float ld[32][33];
    int tid = threadIdx.x;
    for (int i = tid; i < 1024; i += 256) {
        int r = i >> 5, c = i & 31;
        ld[r][c] = src[(size_t)(k0 + r) * Nn + n0 + c];
    }
    __syncthreads();
    for (int i = tid; i < 1024; i += 256) {
        int r = i >> 5, c = i & 31;
        dst[(size_t)(n0 + r) * K + k0 + c] = __float2bfloat16(ld[c][r]);
    }
}

// XOR-swizzle: LDS slot c holds global segment (c&3)^((row>>1)&3) of row c>>2.
// Fragment reads then walk all 32 banks 2-way (free) instead of 8-way.
#define SWZ_SEG(c, row) (((c) & 3) ^ (((row) >> 1) & 3))
#define SWZ_RD(row, quad) (((row) * 4 + ((quad) ^ (((row) >> 1) & 3))) * 8)

// ---------- templated MFMA bf16 GEMM: TM x TN tile, BK=32, 4 waves ----------
// 1-D grid XCD-swizzled: xcd = id&7 owns a bm stripe, bn fastest.
template<int TM, int TN>
__global__ __launch_bounds__(256, 2) void mfma_gemm_t(
    const __hip_bfloat16* __restrict__ A, const __hip_bfloat16* __restrict__ Wt,
    const float* __restrict__ bias, const float* __restrict__ res,
    float* __restrict__ outF, __hip_bfloat16* __restrict__ outB,
    int M, int Nn, int K, int act, int vtmode, int nbm, int nbn) {
    constexpr int WM = TM / 2, WN = TN / 2;
    constexpr int FI = WM / 16, FJ = WN / 16;
    __shared__ __align__(16) __hip_bfloat16 As[TM * 32];
    __shared__ __align__(16) __hip_bfloat16 Bs[TN * 32];
    int id = blockIdx.x;
    int xcd = id & 7, slot = id >> 3;
    int bmb = xcd + 8 * (slot / nbn);
    int bnb = slot % nbn;
    if (bmb >= nbm) return;
    int bm = bmb * TM;
    int bn = bnb * TN;
    int tid = threadIdx.x;
    int lane = tid & 63;
    int wave = tid >> 6;
    int col = lane & 15;
    int quad = lane >> 4;
    int wm = (wave & 1) * WM;
    int wn = (wave >> 1) * WN;
    f32x4 acc[FI][FJ];
    #pragma unroll
    for (int i = 0; i < FI; ++i)
        #pragma unroll
        for (int j = 0; j < FJ; ++j) acc[i][j] = (f32x4){0.f, 0.f, 0.f, 0.f};

    for (int k0 = 0; k0 < K; k0 += 32) {
        #pragma unroll
        for (int cc = 0; cc < TM / 64; ++cc) {
            int cbase = cc * 256 + wave * 64;
            int c = cbase + lane;
            int row = c >> 2;
            int seg = SWZ_SEG(c, row);
            int gm = bm + row; if (gm >= M) gm = M - 1;
            const __hip_bfloat16* ga = A + (size_t)gm * K + k0 + seg * 8;
            __builtin_amdgcn_global_load_lds(
                (const __attribute__((address_space(1))) void*)ga,
                (__attribute__((address_space(3))) void*)(As + (size_t)cbase * 8), 16, 0, 0);
        }
        #pragma unroll
        for (int cc = 0; cc < TN / 64; ++cc) {
            int cbase = cc * 256 + wave * 64;
            int c = cbase + lane;
            int row = c >> 2;
            int seg = SWZ_SEG(c, row);
            int gn = bn + row; if (gn >= Nn) gn = Nn - 1;
            const __hip_bfloat16* gb = Wt + (size_t)gn * K + k0 + seg * 8;
            __builtin_amdgcn_global_load_lds(
                (const __attribute__((address_space(1))) void*)gb,
                (__attribute__((address_space(3))) void*)(Bs + (size_t)cbase * 8), 16, 0, 0);
        }
        __syncthreads();
        bf16x8 af[FI], bfr[FJ];
        #pragma unroll
        for (int i = 0; i < FI; ++i) {
            int ra = wm + i * 16 + col;
            af[i] = *(const bf16x8*)(const void*)&As[SWZ_RD(ra, quad)];
        }
        #pragma unroll
        for (int j = 0; j < FJ; ++j) {
            int rb = wn + j * 16 + col;
            bfr[j] = *(const bf16x8*)(const void*)&Bs[SWZ_RD(rb, quad)];
        }
        #pragma unroll
        for (int i = 0; i < FI; ++i)
            #pragma unroll
            for (int j = 0; j < FJ; ++j)
                acc[i][j] = __builtin_amdgcn_mfma_f32_16x16x32_bf16(af[i], bfr[j], acc[i][j], 0, 0, 0);
        __syncthreads();
    }
    #pragma unroll
    for (int i = 0; i < FI; ++i) {
        int gmb = bm + wm + i * 16 + quad * 4;
        #pragma unroll
        for (int j = 0; j < FJ; ++j) {
            int gn = bn + wn + j * 16 + col;
            if (gn >= Nn) continue;
            float bs = bias[gn];
            #pragma unroll
            for (int r = 0; r < 4; ++r) {
                int gm = gmb + r;
                if (gm >= M) continue;
                float v = acc[i][j][r] + bs;
                if (act == 1) v = 0.5f * v * (1.f + erff(v * 0.70710678118654752f));
                if (res) v += res[(size_t)gm * Nn + gn];
                if (outF) outF[(size_t)gm * Nn + gn] = v;
                if (outB) {
                    if (vtmode) {
                        int bb = gm / T;
                        int tt = gm - bb * T;
                        outB[((size_t)bb * 512 + gn) * VTS + tt] = __float2bfloat16(v);
                    } else {
                        outB[(size_t)gm * Nn + gn] = __float2bfloat16(v);
                    }
                }
            }
        }
    }
}

// ---------- fused QKV GEMM: 64x64 tiles over N=1536, routed epilogue ----------
__global__ __launch_bounds__(256, 2) void qkv_gemm(
    const __hip_bfloat16* __restrict__ A, const __hip_bfloat16* __restrict__ Wt,
    const float* __restrict__ bq, const float* __restrict__ bk, const float* __restrict__ bv,
    __hip_bfloat16* __restrict__ qb, __hip_bfloat16* __restrict__ kb,
    __hip_bfloat16* __restrict__ vt, int nbm, int nbn) {
    const int M = B * T, K = D, Nn = 1536;
    __shared__ __align__(16) __hip_bfloat16 As[64 * 32];
    __shared__ __align__(16) __hip_bfloat16 Bs[64 * 32];
    int id = blockIdx.x;
    int xcd = id & 7, slot = id >> 3;
    int bmb = xcd + 8 * (slot / nbn);
    int bnb = slot % nbn;
    if (bmb >= nbm) return;
    int bm = bmb * 64;
    int bn = bnb * 64;
    int tid = threadIdx.x;
    int lane = tid & 63;
    int wave = tid >> 6;
    int col = lane & 15;
    int quad = lane >> 4;
    int wm = (wave & 1) * 32;
    int wn = (wave >> 1) * 32;
    f32x4 acc[2][2];
    #pragma unroll
    for (int i = 0; i < 2; ++i)
        #pragma unroll
        for (int j = 0; j < 2; ++j) acc[i][j] = (f32x4){0.f, 0.f, 0.f, 0.f};

    for (int k0 = 0; k0 < K; k0 += 32) {
        {
            int cbase = wave * 64;
            int c = cbase + lane;
            int row = c >> 2;
            int seg = SWZ_SEG(c, row);
            int gm = bm + row; if (gm >= M) gm = M - 1;
            const __hip_bfloat16* ga = A + (size_t)gm * K + k0 + seg * 8;
            __builtin_amdgcn_global_load_lds(
                (const __attribute__((address_space(1))) void*)ga,
                (__attribute__((address_space(3))) void*)(As + (size_t)cbase * 8), 16, 0, 0);
            int gn = bn + row;
            const __hip_bfloat16* gb = Wt + (size_t)gn * K + k0 + seg * 8;
            __builtin_amdgcn_global_load_lds(
                (const __attribute__((address_space(1))) void*)gb,
                (__attribute__((address_space(3))) void*)(Bs + (size_t)cbase * 8), 16, 0, 0);
        }
        __syncthreads();
        bf16x8 af[2], bfr[2];
        #pragma unroll
        for (int i = 0; i < 2; ++i) {
            int ra = wm + i * 16 + col;
            af[i] = *(const bf16x8*)(const void*)&As[SWZ_RD(ra, quad)];
        }
        #pragma unroll
        for (int j = 0; j < 2; ++j) {
            int rb = wn + j * 16 + col;
            bfr[j] = *(const bf16x8*)(const void*)&Bs[SWZ_RD(rb, quad)];
        }
        #pragma unroll
        for (int i = 0; i < 2; ++i)
            #pragma unroll
            for (int j = 0; j < 2; ++j)
                acc[i][j] = __builtin_amdgcn_mfma_f32_16x16x32_bf16(af[i], bfr[j], acc[i][j], 0, 0, 0);
        __syncthreads();
    }
    int sel = bn >> 9;            // block-uniform: 0=Q 1=K 2=V
    const float* bias = sel == 0 ? bq : sel == 1 ? bk : bv;
    #pragma unroll
    for (int i = 0; i < 2; ++i) {
        int gmb = bm + wm + i * 16 + quad * 4;
        #pragma unroll
        for (int j = 0; j < 2; ++j) {
            int gn = bn + wn + j * 16 + col;
            int gl = gn & 511;
            float bs = bias[gl];
            #pragma unroll
            for (int r = 0; r < 4; ++r) {
                int gm = gmb + r;
                if (gm >= M) continue;
                float v = acc[i][j][r] + bs;
                if (sel == 0)      qb[(size_t)gm * 512 + gl] = __float2bfloat16(v);
                else if (sel == 1) kb[(size_t)gm * 512 + gl] = __float2bfloat16(v);
                else {
                    int bb = gm / T;
                    int tt = gm - bb * T;
                    vt[((size_t)bb * 512 + gl) * VTS + tt] = __float2bfloat16(v);
                }
            }
        }
    }
}

// ---------- flash-style MFMA attention (guide gate staged in LDS) ----------
__global__ __launch_bounds__(256) void attn_flash_kernel(
    const __hip_bfloat16* __restrict__ qb, const __hip_bfloat16* __restrict__ kb,
    const __hip_bfloat16* __restrict__ vt, const __hip_bfloat16* __restrict__ gd,
    __hip_bfloat16* __restrict__ ctxb) {
    __shared__ __align__(16) __hip_bfloat16 Ks[64][72];
    __shared__ __align__(16) __hip_bfloat16 Vs[64][72];
    __shared__ __align__(16) __hip_bfloat16 Pw[4][16][72];
    __shared__ __align__(16) __hip_bfloat16 Gs[64][68];
    int bid = blockIdx.x;
    int sg = bid % 9;
    int h = (bid / 9) % H;
    int b = bid / (9 * H);
    int tid = threadIdx.x;
    int wave = tid >> 6, lane = tid & 63;
    int col = lane & 15, quad = lane >> 4;
    int q0b = sg * 64;
    int q0 = q0b + wave * 16;

    int qr = q0 + col; if (qr > T - 1) qr = T - 1;
    const __hip_bfloat16* qptr = qb + (size_t)(b * T + qr) * D + h * E + quad * 8;
    bf16x8 a0 = *(const bf16x8*)(const void*)qptr;
    bf16x8 a1 = *(const bf16x8*)(const void*)(qptr + 32);

    float m_r[4] = {-1e30f, -1e30f, -1e30f, -1e30f};
    float S[4] = {0.f, 0.f, 0.f, 0.f};
    float G[4] = {0.f, 0.f, 0.f, 0.f};
    f32x4 o[4];
    #pragma unroll
    for (int j = 0; j < 4; ++j) o[j] = (f32x4){0.f, 0.f, 0.f, 0.f};

    const __hip_bfloat16* vbase = vt + (size_t)((b * H + h) * E) * VTS;

    for (int kc = 0; kc < NCHUNK; ++kc) {
        __syncthreads();
        #pragma unroll
        for (int i = 0; i < 2; ++i) {
            int idx = tid + i * 256;
            int r = idx >> 3, s = idx & 7;
            int kr = kc * 64 + r; int krc = kr > T - 1 ? T - 1 : kr;
            *(bf16x8*)(void*)&Ks[r][s * 8] =
                *(const bf16x8*)(const void*)(kb + (size_t)(b * T + krc) * D + h * E + s * 8);
            *(bf16x8*)(void*)&Vs[r][s * 8] =
                *(const bf16x8*)(const void*)(vbase + (size_t)r * VTS + kc * 64 + s * 8);
            bf16x8 gval;
            int grow = q0b + r;
            if (grow < N && kc < 8) {
                gval = *(const bf16x8*)(const void*)(gd + ((size_t)b * N + grow) * N + kc * 64 + s * 8);
            } else {
                gval = (bf16x8){0x3F00, 0x3F00, 0x3F00, 0x3F00, 0x3F00, 0x3F00, 0x3F00, 0x3F00};
            }
            *(bf16x8*)(void*)&Gs[r][s * 8] = gval;
        }
        __syncthreads();
        f32x4 sc[4];
        #pragma unroll
        for (int sub = 0; sub < 4; ++sub) {
            bf16x8 b0 = *(const bf16x8*)(const void*)&Ks[sub * 16 + col][quad * 8];
            bf16x8 b1 = *(const bf16x8*)(const void*)&Ks[sub * 16 + col][32 + quad * 8];
            f32x4 acc = (f32x4){0.f, 0.f, 0.f, 0.f};
            acc = __builtin_amdgcn_mfma_f32_16x16x32_bf16(a0, b0, acc, 0, 0, 0);
            acc = __builtin_amdgcn_mfma_f32_16x16x32_bf16(a1, b1, acc, 0, 0, 0);
            sc[sub] = acc;
        }
        float cm[4] = {-1e30f, -1e30f, -1e30f, -1e30f};
        #pragma unroll
        for (int sub = 0; sub < 4; ++sub) {
            int key = kc * 64 + sub * 16 + col;
            #pragma unroll
            for (int r = 0; r < 4; ++r) {
                float v = sc[sub][r] * 0.125f;
                if (key >= T) v = -1e30f;
                sc[sub][r] = v;
                cm[r] = fmaxf(cm[r], v);
            }
        }
        #pragma unroll
        for (int r = 0; r < 4; ++r)
            #pragma unroll
            for (int d = 1; d < 16; d <<= 1) cm[r] = fmaxf(cm[r], __shfl_xor(cm[r], d, 64));
        float alpha[4];
        #pragma unroll
        for (int r = 0; r < 4; ++r) {
            float mn = fmaxf(m_r[r], cm[r]);
            alpha[r] = __expf(m_r[r] - mn);
            m_r[r] = mn;
            S[r] *= alpha[r];
            G[r] *= alpha[r];
        }
        #pragma unroll
        for (int j = 0; j < 4; ++j)
            #pragma unroll
            for (int r = 0; r < 4; ++r) o[j][r] *= alpha[r];
        #pragma unroll
        for (int sub = 0; sub < 4; ++sub) {
            #pragma unroll
            for (int r = 0; r < 4; ++r) {
                float p = __expf(sc[sub][r] - m_r[r]);
                S[r] += p;
                float g = __bfloat162float(Gs[wave * 16 + quad * 4 + r][sub * 16 + col]);
                float t = p * g;
                G[r] += t;
                Pw[wave][quad * 4 + r][sub * 16 + col] = __float2bfloat16(t);
            }
        }
        #pragma unroll
        for (int ks = 0; ks < 2; ++ks) {
            bf16x8 pa = *(const bf16x8*)(const void*)&Pw[wave][col][ks * 32 + quad * 8];
            #pragma unroll
            for (int j = 0; j < 4; ++j) {
                bf16x8 bv = *(const bf16x8*)(const void*)&Vs[j * 16 + col][ks * 32 + quad * 8];
                o[j] = __builtin_amdgcn_mfma_f32_16x16x32_bf16(pa, bv, o[j], 0, 0, 0);
            }
        }
    }
    #pragma unroll
    for (int r = 0; r < 4; ++r) {
        #pragma unroll
        for (int d = 1; d < 16; d <<= 1) {
            S[r] += __shfl_xor(S[r], d, 64);
            G[r] += __shfl_xor(G[r], d, 64);
        }
    }
    float inv[4];
    #pragma unroll
    for (int r = 0; r < 4; ++r) inv[r] = 1.f / (G[r] + 1e-6f * S[r]);
    #pragma unroll
    for (int j = 0; j < 4; ++j)
        #pragma unroll
        for (int r = 0; r < 4; ++r) {
            int row = q0 + quad * 4 + r;
            if (row < T)
                ctxb[(size_t)(b * T + row) * D + h * E + j * 16 + col] =
                    __float2bfloat16(o[j][r] * inv[r]);
        }
}

// ---------- layernorm: wave-per-row, no barriers ----------
__global__ __launch_bounds__(256) void ln_kernel(const float* __restrict__ in, const float* __restrict__ g,
                          const float* __restrict__ bb, float* __restrict__ outF,
                          __hip_bfloat16* __restrict__ outB) {
    int row = blockIdx.x * 4 + (threadIdx.x >> 6);
    int lane = threadIdx.x & 63;
    const float* base = in + (size_t)row * D + lane * 8;
    float4 u0 = *(const float4*)base;
    float4 u1 = *(const float4*)(base + 4);
    float s = (u0.x + u0.y) + (u0.z + u0.w) + (u1.x + u1.y) + (u1.z + u1.w);
    float ss = u0.x * u0.x + u0.y * u0.y + u0.z * u0.z + u0.w * u0.w
             + u1.x * u1.x + u1.y * u1.y + u1.z * u1.z + u1.w * u1.w;
    #pragma unroll
    for (int d = 1; d < 64; d <<= 1) {
        s += __shfl_xor(s, d, 64);
        ss += __shfl_xor(ss, d, 64);
    }
    float m = s * (1.f / (float)D);
    float var = ss * (1.f / (float)D) - m * m;
    float rstd = rsqrtf(fmaxf(var, 0.f) + 1e-5f);
    float4 g0 = *(const float4*)(g + lane * 8);
    float4 g1 = *(const float4*)(g + lane * 8 + 4);
    float4 b0 = *(const float4*)(bb + lane * 8);
    float4 b1 = *(const float4*)(bb + lane * 8 + 4);
    float4 o0, o1;
    o0.x = (u0.x - m) * rstd * g0.x + b0.x;
    o0.y = (u0.y - m) * rstd * g0.y + b0.y;
    o0.z = (u0.z - m) * rstd * g0.z + b0.z;
    o0.w = (u0.w - m) * rstd * g0.w + b0.w;
    o1.x = (u1.x - m) * rstd * g1.x + b1.x;
    o1.y = (u1.y - m) * rstd * g1.y + b1.y;
    o1.z = (u1.z - m) * rstd * g1.z + b1.z;
    o1.w = (u1.w - m) * rstd * g1.w + b1.w;
    *(float4*)(outF + (size_t)row * D + lane * 8) = o0;
    *(float4*)(outF + (size_t)row * D + lane * 8 + 4) = o1;
    __align__(16) __hip_bfloat16 tmp[8];
    tmp[0] = __float2bfloat16(o0.x); tmp[1] = __float2bfloat16(o0.y);
    tmp[2] = __float2bfloat16(o0.z); tmp[3] = __float2bfloat16(o0.w);
    tmp[4] = __float2bfloat16(o1.x); tmp[5] = __float2bfloat16(o1.y);
    tmp[6] = __float2bfloat16(o1.z); tmp[7] = __float2bfloat16(o1.w);
    *(bf16x8*)(void*)(outB + (size_t)row * D + lane * 8) = *(const bf16x8*)(const void*)tmp;
}

// ---------- final: LDS-tiled transpose + RevIN inverse ----------
__global__ __launch_bounds__(256) void revin_inv_kernel(
    const float* __restrict__ dec, const float* __restrict__ beta,
    const float* __restrict__ gamma, const float* __restrict__ mean,
    const float* __restrict__ stdv, float* __restrict__ out) {
    __shared__ float tile[64][33];
    int b = blockIdx.x;
    int n0 = blockIdx.y * 64;
    int p0 = blockIdx.z * 32;
    int t = threadIdx.x;
    int pl = t & 31, nb = t >> 5;
    #pragma unroll
    for (int i = 0; i < 8; ++i) {
        int nl = nb + i * 8;
        tile[nl][pl] = dec[((size_t)b * T + n0 + nl) * PRED + p0 + pl];
    }
    __syncthreads();
    int nl = t & 63, pb = t >> 6;
    int n = n0 + nl;
    int bn = b * N + n;
    float be = beta[n], ga = gamma[n], sd = stdv[bn], mn = mean[bn];
    float scale = sd / (ga + 1e-5f);
    #pragma unroll
    for (int i = 0; i < 8; ++i) {
        int p = p0 + pb + i * 4;
        out[((size_t)b * PRED + p) * N + n] = (tile[nl][pb + i * 4] - be) * scale + mn;
    }
}

static inline int swz_grid(int nbm, int nbn) { return 8 * ((nbm + 7) / 8) * nbn; }

extern "C" void kernel_launch(void* const* d_in, const int* in_sizes, int n_in,
                              void* d_out, int out_size, void* d_ws, size_t ws_size,
                              hipStream_t stream) {
    const float* x_enc  = (const float*)d_in[0];
    const float* x_mark = (const float*)d_in[1];
    const float* gamma  = (const float*)d_in[4];
    const float* beta   = (const float*)d_in[5];
    const float* tp_w1  = (const float*)d_in[6];
    const float* tp_b1  = (const float*)d_in[7];
    const float* tp_w2  = (const float*)d_in[8];
    const float* tp_b2  = (const float*)d_in[9];
    const float* emb_w  = (const float*)d_in[10];
    const float* emb_b  = (const float*)d_in[11];
    const float* wq = (const float*)d_in[12];
    const float* bq = (const float*)d_in[13];
    const float* wk = (const float*)d_in[14];
    const float* bk = (const float*)d_in[15];
    const float* wv = (const float*)d_in[16];
    const float* bv = (const float*)d_in[17];
    const float* wo = (const float*)d_in[18];
    const float* bo = (const float*)d_in[19];
    const float* w1 = (const float*)d_in[20];
    const float* b1 = (const float*)d_in[21];
    const float* w2 = (const float*)d_in[22];
    const float* b2 = (const float*)d_in[23];
    const float* ln1g = (const float*)d_in[24];
    const float* ln1b = (const float*)d_in[25];
    const float* ln2g = (const float*)d_in[26];
    const float* ln2b = (const float*)d_in[27];
    const float* normg = (const float*)d_in[28];
    const float* normb = (const float*)d_in[29];
    const float* proj_w = (const float*)d_in[30];
    const float* proj_b = (const float*)d_in[31];

    char* ws = (char*)d_ws;
    float* mean = (float*)(ws + WS_MEAN);
    float* stdv = (float*)(ws + WS_STD);
    __hip_bfloat16* gd  = (__hip_bfloat16*)(ws + WS_GD);
    float* x            = (float*)(ws + WS_X);
    __hip_bfloat16* xb  = (__hip_bfloat16*)(ws + WS_XB);
    __hip_bfloat16* wts = (__hip_bfloat16*)(ws + WS_WTS);
    __hip_bfloat16* qbuf = (__hip_bfloat16*)(ws + WS_QB);
    __hip_bfloat16* kbuf = (__hip_bfloat16*)(ws + WS_KB);
    __hip_bfloat16* vt   = (__hip_bfloat16*)(ws + WS_VT);
    float* xt  = (float*)(ws + WS_KB);
    float* nt  = (float*)(ws + WS_VT);
    __hip_bfloat16* tokb = (__hip_bfloat16*)(ws + WS_QB);
    __hip_bfloat16* ctxb = xb;
    __hip_bfloat16* ffnb = (__hip_bfloat16*)(ws + WS_QB);
    float* dec = (float*)(ws + WS_QB);

    revin_stats_kernel<<<(B * N + 255) / 256, 256, 0, stream>>>(x_enc, mean, stdv);
    norm_transpose_kernel<<<(B * N * L + 255) / 256, 256, 0, stream>>>(x_enc, mean, stdv, gamma, beta, xt);
    trend_nt_kernel<<<B * N, 128, 0, stream>>>(xt, tp_w1, tp_b1, tp_w2, tp_b2, nt);
    guide_kernel<<<dim3(N / 16, N / 16, B), dim3(16, 16), 0, stream>>>(nt, gd);
    // vt aliases nt: stale f32 bytes as bf16 can be NaN in pad tokens; 0*NaN=NaN
    // in the PV MFMA. Zero once per launch (layer GEMMs rewrite tokens 0..515).
    hipMemsetAsync(vt, 0, VT_BYTES, stream);
    build_tok_kernel<<<(B * T * L + 255) / 256, 256, 0, stream>>>(xt, x_mark, tokb);
    wconv_kernel<<<6240, 256, 0, stream>>>(wq, wk, wv, wo, w1, w2, emb_w, proj_w, wts);

    const int M = B * T;                   // 8256
    const int NBM64 = (M + 63) / 64;       // 129
    const int NBM128 = (M + 127) / 128;    // 65
    mfma_gemm_t<64, 64><<<swz_grid(NBM64, 8), 256, 0, stream>>>(
        tokb, wts + WT_EMB, emb_b, nullptr, x, xb, M, D, L, 0, 0, NBM64, 8);
    for (int i = 0; i < 2; ++i) {
        const __hip_bfloat16* qkvT = wts + WT_QKV + (size_t)i * 1536 * 512;
        const __hip_bfloat16* woT  = wts + WT_WO + (size_t)i * D * D;
        qkv_gemm<<<swz_grid(NBM64, 24), 256, 0, stream>>>(
            xb, qkvT, bq + i * D, bk + i * D, bv + i * D, qbuf, kbuf, vt, NBM64, 24);
        attn_flash_kernel<<<B * H * 9, 256, 0, stream>>>(qbuf, kbuf, vt, gd, ctxb);
        mfma_gemm_t<64, 64><<<swz_grid(NBM64, 8), 256, 0, stream>>>(
            ctxb, woT, bo + i * D, x, x, nullptr, M, D, D, 0, 0, NBM64, 8);
        ln_kernel<<<M / 4, 256, 0, stream>>>(x, ln1g + i * D, ln1b + i * D, x, xb);
        mfma_gemm_t<128, 128><<<swz_grid(NBM128, 16), 256, 0, stream>>>(
            xb, wts + WT_W1 + (size_t)i * DFF * D, b1 + i * DFF, nullptr,
            nullptr, ffnb, M, DFF, D, 1, 0, NBM128, 16);
        mfma_gemm_t<64, 64><<<swz_grid(NBM64, 8), 256, 0, stream>>>(
            ffnb, wts + WT_W2 + (size_t)i * DFF * D, b2 + i * D, x, x, nullptr,
            M, D, DFF, 0, 0, NBM64, 8);
        ln_kernel<<<M / 4, 256, 0, stream>>>(x, ln2g + i * D, ln2b + i * D, x, xb);
    }
    ln_kernel<<<M / 4, 256, 0, stream>>>(x, normg, normb, x, xb);
    mfma_gemm_t<64, 64><<<swz_grid(NBM64, 2), 256, 0, stream>>>(
        xb, wts + WT_PROJ, proj_b, nullptr, dec, nullptr, M, PRED, D, 0, 0, NBM64, 2);
    revin_inv_kernel<<<dim3(B, N / 64, PRED / 32), 256, 0, stream>>>(dec, beta, gamma, mean, stdv,
                                                                     (float*)d_out);
}